// Round 4
// baseline (484.436 us; speedup 1.0000x reference)
//
#include <hip/hip_runtime.h>

#define NN 16
#define BB 512
#define DD 256
#define RR (NN*BB)   // 8192

typedef __attribute__((ext_vector_type(8))) short v8s;
typedef __attribute__((ext_vector_type(4))) float v4f;

#define MFMA16(a,b,c) __builtin_amdgcn_mfma_f32_16x16x32_bf16((a),(b),(c),0,0,0)

// counted waits: raw asm + sched fence (rule #18)
#define WAITV(N)  do{ asm volatile("s_waitcnt vmcnt(" #N ")" ::: "memory"); __builtin_amdgcn_sched_barrier(0); }while(0)
#define WAITVL(N) do{ asm volatile("s_waitcnt vmcnt(" #N ") lgkmcnt(0)" ::: "memory"); __builtin_amdgcn_sched_barrier(0); }while(0)
#define SCHED0()  __builtin_amdgcn_sched_barrier(0)
#define BARRIER() do{ asm volatile("s_waitcnt lgkmcnt(0)" ::: "memory"); __builtin_amdgcn_sched_barrier(0); __builtin_amdgcn_s_barrier(); __builtin_amdgcn_sched_barrier(0); }while(0)

__device__ __forceinline__ unsigned short f2bf(float f){
  unsigned int x = __float_as_uint(f);
  x += 0x7fffu + ((x >> 16) & 1u);
  return (unsigned short)(x >> 16);
}
__device__ __forceinline__ float bf2f(unsigned short u){
  return __uint_as_float(((unsigned int)u) << 16);
}

// ---------- prep kernels ----------

__global__ __launch_bounds__(256) void k_cast4(const float* __restrict__ in,
                                               unsigned short* __restrict__ out, int n4){
  int idx = blockIdx.x * 256 + threadIdx.x;
  if (idx < n4){
    float4 v = ((const float4*)in)[idx];
    ushort4 o;
    o.x = f2bf(v.x); o.y = f2bf(v.y); o.z = f2bf(v.z); o.w = f2bf(v.w);
    ((ushort4*)out)[idx] = o;
  }
}

// all weight transposes + concat + bias concat in one launch
// Wcat [1536][256]: rows 0..511 = tW1^T ; rows 512..1023 = iW1-top^T ; 1024..1535 = iW1-bot^T
// bcat [1536] = [tb1 | 0 | ib1]
__global__ __launch_bounds__(256) void k_prep(
    const float* __restrict__ tW1, const float* __restrict__ tW2, const float* __restrict__ tW3,
    const float* __restrict__ iW1, const float* __restrict__ iW2, const float* __restrict__ iW3,
    const float* __restrict__ tb1, const float* __restrict__ ib1,
    unsigned short* __restrict__ Wcat, unsigned short* __restrict__ tW2t, unsigned short* __restrict__ tW3t,
    unsigned short* __restrict__ iW2t, unsigned short* __restrict__ iW3t,
    float* __restrict__ bcat){
  int idx = blockIdx.x * 256 + threadIdx.x;
  if (idx < 131072){                                   // Wcat rows 0..511 <- tW1 [256][512]
    int n = idx >> 8, k = idx & 255;
    Wcat[idx] = f2bf(tW1[k * 512 + n]);
    return;
  }
  idx -= 131072;
  if (idx < 262144){                                   // tW2t [512][512]
    int n = idx >> 9, k = idx & 511;
    tW2t[idx] = f2bf(tW2[k * 512 + n]);
    return;
  }
  idx -= 262144;
  if (idx < 131072){                                   // tW3t [256][512] <- tW3 [512][256]
    int n = idx >> 9, k = idx & 511;
    tW3t[idx] = f2bf(tW3[k * 256 + n]);
    return;
  }
  idx -= 131072;
  if (idx < 262144){                                   // iW2t [512][512]
    int n = idx >> 9, k = idx & 511;
    iW2t[idx] = f2bf(iW2[k * 512 + n]);
    return;
  }
  idx -= 262144;
  if (idx < 131072){                                   // iW3t [256][512]
    int n = idx >> 9, k = idx & 511;
    iW3t[idx] = f2bf(iW3[k * 256 + n]);
    return;
  }
  idx -= 131072;
  if (idx < 262144){                                   // Wcat rows 512..1535 <- iW1 split
    int r = idx >> 8, k = idx & 255;
    float v = (r < 512) ? iW1[k * 512 + r] : iW1[(k + 256) * 512 + (r - 512)];
    Wcat[(512 << 8) + idx] = f2bf(v);
    return;
  }
  idx -= 262144;
  if (idx < 1536)
    bcat[idx] = (idx < 512) ? tb1[idx] : ((idx < 1024) ? 0.f : ib1[idx - 1024]);
}

// ---------- phase-A GEMM ----------
template<int KD, bool OUTBF16, bool RELU, bool ADDX, bool SPLIT>
__global__ __launch_bounds__(256) void k_gemm(const unsigned short* __restrict__ A,
                                              const unsigned short* __restrict__ Wt,
                                              const float* __restrict__ bias,
                                              void* __restrict__ Cout,
                                              const float* __restrict__ extra,
                                              void* __restrict__ Cout2,
                                              int M, int Nn){
  __shared__ __align__(16) unsigned char sA[64 * 128];
  __shared__ __align__(16) unsigned char sB[128 * 128];
  const int m0 = blockIdx.x * 64;
  const int n0 = blockIdx.y * 128;
  const int t = threadIdx.x;
  const int w = t >> 6, l = t & 63;
  const int l15 = l & 15, lq = l >> 4;
  const int rowh = (w & 1) * 32, colh = (w >> 1) * 64;

  v4f c[2][4];
#pragma unroll
  for (int r = 0; r < 2; r++)
#pragma unroll
    for (int q = 0; q < 4; q++) c[r][q] = (v4f){0.f, 0.f, 0.f, 0.f};

  for (int kt = 0; kt < KD; kt += 64){
    __syncthreads();
    {
      const int row = t >> 2, cq = (t & 3) * 16;
      const unsigned short* src = A + (size_t)(m0 + row) * KD + kt + cq;
      v8s a0 = *(const v8s*)(src);
      v8s a1 = *(const v8s*)(src + 8);
      const unsigned sw = (unsigned)((row & 7) << 4);
      *(v8s*)(sA + ((unsigned)((row << 7) + (cq << 1)) ^ sw)) = a0;
      *(v8s*)(sA + ((unsigned)((row << 7) + (cq << 1) + 16) ^ sw)) = a1;
    }
    {
      const int n = t & 127, kq = (t >> 7) * 32;
      const unsigned short* src = Wt + (size_t)(n0 + n) * KD + kt + kq;
      const unsigned base = (unsigned)((n << 7) + (kq << 1));
      const unsigned sw = (unsigned)((n & 7) << 4);
#pragma unroll
      for (int q = 0; q < 4; q++){
        v8s v = *(const v8s*)(src + q * 8);
        *(v8s*)(sB + ((base + q * 16) ^ sw)) = v;
      }
    }
    __syncthreads();
#pragma unroll
    for (int kb = 0; kb < 64; kb += 32){
      v8s af[2], bfr[4];
#pragma unroll
      for (int r = 0; r < 2; r++){
        const int row = rowh + r * 16 + l15;
        af[r] = *(const v8s*)(sA + ((unsigned)((row << 7) + ((kb + (lq << 3)) << 1)) ^ (unsigned)((row & 7) << 4)));
      }
#pragma unroll
      for (int q = 0; q < 4; q++){
        const int n = colh + q * 16 + l15;
        bfr[q] = *(const v8s*)(sB + ((unsigned)((n << 7) + ((kb + (lq << 3)) << 1)) ^ (unsigned)((n & 7) << 4)));
      }
#pragma unroll
      for (int r = 0; r < 2; r++)
#pragma unroll
        for (int q = 0; q < 4; q++)
          c[r][q] = MFMA16(af[r], bfr[q], c[r][q]);
    }
  }
#pragma unroll
  for (int r = 0; r < 2; r++){
#pragma unroll
    for (int q = 0; q < 4; q++){
      const int col = n0 + colh + q * 16 + l15;
      const float bv = bias ? bias[col] : 0.0f;
#pragma unroll
      for (int e = 0; e < 4; e++){
        const int row = m0 + rowh + r * 16 + (lq << 2) + e;
        float v = c[r][q][e] + bv;
        if (SPLIT){
          if (col < 512){
            ((unsigned short*)Cout)[(size_t)row * 512 + col] = f2bf(fmaxf(v, 0.0f));
          } else {
            ((unsigned short*)Cout2)[(size_t)row * 1024 + (col - 512)] = f2bf(v);
          }
        } else {
          if (RELU) v = fmaxf(v, 0.0f);
          if (ADDX) v += extra[(size_t)row * Nn + col];
          if (OUTBF16) ((unsigned short*)Cout)[(size_t)row * Nn + col] = f2bf(v);
          else         ((float*)Cout)[(size_t)row * Nn + col] = v;
        }
      }
    }
  }
}

// ---------- fused pair kernel v3 ----------
// 256 WGs = 16 i x 4 row-quarters(128) x 4 j-groups ({4,4,4,3} of the 15 j).
// 512 threads (8 waves), 160 KB LDS (sA1 dbuf 2x16KB + sA2 128KB).
// Counted-vmcnt pipeline, raw barriers (prefetches ride across), setprio on MFMA.
// Per j: GEMM2 in 2 n-passes x 8 K-steps (c2 64 VGPR), A2->sA2, barrier-free GEMM3,
// acc += relu(GEMM3+b3) across j. Epilogue: f32 partial slab; k_reduce sums 4.
__global__ __launch_bounds__(512, 2) void k_pair3(
    const unsigned short* __restrict__ UV,   // [8192][1024] bf16: U' | V'+ib1
    const unsigned short* __restrict__ W2t,  // [512][512] bf16 (n,k)
    const unsigned short* __restrict__ W3t,  // [256][512] bf16 (n,k)
    const float* __restrict__ b2,
    const float* __restrict__ b3,
    float* __restrict__ Pp){                 // [64][512][256] f32 partials
  __shared__ __align__(16) unsigned char sA1[2][128 * 128];  // 2 x 16 KB
  __shared__ __align__(16) unsigned char sA2[128 * 1024];    // 128 KB

  const int bid = blockIdx.x;
  const int jg = bid & 3;
  const int q4 = (bid >> 2) & 3;
  const int i  = bid >> 4;
  const int b0 = q4 * 128;
  const int jb = jg * 4;
  const int jcnt = (jg == 3) ? 3 : 4;

  const int t = threadIdx.x, w = t >> 6, l = t & 63, l15 = l & 15, lq = l >> 4;
  const unsigned rsw = (unsigned)((l15 & 7) << 4);

  // staging map: 512 threads -> 128 rows x 64 k (4 threads/row, 16 k each)
  const int sr = t >> 2, sk = (t & 3) * 16;
  const unsigned short* Ubase = UV + ((size_t)(i * BB + b0 + sr) << 10) + sk;
  const size_t vconst = ((size_t)(b0 + sr) << 10) + 512 + sk;
  const unsigned a1wa = ((unsigned)((sr << 7) + (sk << 1))) ^ ((unsigned)((sr & 7) << 4));
  const unsigned a1wb = ((unsigned)((sr << 7) + (sk << 1) + 16)) ^ ((unsigned)((sr & 7) << 4));

  const unsigned short* W2l = W2t + ((size_t)(w * 32 + l15) << 9) + lq * 8;
  const unsigned short* W3l = W3t + ((size_t)(w * 32 + l15) << 9) + lq * 8;
  const float b3v0 = b3[w * 32 + l15];
  const float b3v1 = b3[w * 32 + 16 + l15];

  v8s u0, u1, v0, v1;
  v8s w2a[2], w2b[2];

  v4f c2[2][8], acc[8][2];
#pragma unroll
  for (int nf = 0; nf < 2; nf++)
#pragma unroll
    for (int mf = 0; mf < 8; mf++) c2[nf][mf] = (v4f){0.f, 0.f, 0.f, 0.f};
#pragma unroll
  for (int mf = 0; mf < 8; mf++)
#pragma unroll
    for (int nf = 0; nf < 2; nf++) acc[mf][nf] = (v4f){0.f, 0.f, 0.f, 0.f};

  auto conv_to = [&](unsigned char* dst){
    v8s p0, p1;
#pragma unroll
    for (int e = 0; e < 8; e++){
      p0[e] = (short)f2bf(fmaxf(bf2f((unsigned short)u0[e]) + bf2f((unsigned short)v0[e]), 0.f));
      p1[e] = (short)f2bf(fmaxf(bf2f((unsigned short)u1[e]) + bf2f((unsigned short)v1[e]), 0.f));
    }
    *(v8s*)(dst + a1wa) = p0;
    *(v8s*)(dst + a1wb) = p1;
  };
  auto ldw2 = [&](int h, int kt, int kb, int nf)->v8s{
    return *(const v8s*)(W2l + (((size_t)(h * 256 + nf * 16)) << 9) + kt * 64 + kb * 32);
  };
  auto ldw3 = [&](int it, int nf)->v8s{
    return *(const v8s*)(W3l + (((size_t)(nf * 16)) << 9) + it * 32);
  };

  // ---- prologue: prime UV(0), convert to buf0, issue UV(1) + w2f(s0,kb0) ----
  {
    int rj = jb; int j0 = rj + (rj >= i ? 1 : 0);
    const unsigned short* Vc0 = UV + ((size_t)j0 << 19) + vconst;
    u0 = *(const v8s*)(Ubase);      u1 = *(const v8s*)(Ubase + 8);
    v0 = *(const v8s*)(Vc0);        v1 = *(const v8s*)(Vc0 + 8);
    WAITV(0);
    conv_to(&sA1[0][0]);
    SCHED0();
    u0 = *(const v8s*)(Ubase + 64); u1 = *(const v8s*)(Ubase + 72);
    v0 = *(const v8s*)(Vc0 + 64);   v1 = *(const v8s*)(Vc0 + 72);
    SCHED0();
    w2a[0] = ldw2(0, 0, 0, 0); w2a[1] = ldw2(0, 0, 0, 1);
    BARRIER();
  }

  int rjc = jb; int jc = rjc + (rjc >= i ? 1 : 0);
  const unsigned short* Vc = UV + ((size_t)jc << 19) + vconst;

  for (int jj = 0; jj < jcnt; ++jj){
    const int rjn = jb + (jj + 1 < jcnt ? jj + 1 : jcnt - 1);
    const int jn = rjn + (rjn >= i ? 1 : 0);
    const unsigned short* Vn = UV + ((size_t)jn << 19) + vconst;

    // ---- GEMM2: 16 steps (2 n-passes x 8 K-tiles) ----
#pragma unroll
    for (int s = 0; s < 16; ++s){
      const int kt = s & 7, h = s >> 3;
      WAITV(2);                            // UV(s+1) ready
      conv_to(&sA1[(s + 1) & 1][0]);       // build A1(s+1)
      SCHED0();
      {                                    // issue UV(s+2)
        const int x = s + 2; const int xo = (x & 7) * 64;
        const unsigned short* vb = (x >= 16) ? Vn : Vc;
        u0 = *(const v8s*)(Ubase + xo); u1 = *(const v8s*)(Ubase + xo + 8);
        v0 = *(const v8s*)(vb + xo);    v1 = *(const v8s*)(vb + xo + 8);
      }
      SCHED0();
      const unsigned char* bufc = &sA1[s & 1][0];
      { // kb0
        v8s a1f[8];
#pragma unroll
        for (int mf = 0; mf < 8; mf++)
          a1f[mf] = *(const v8s*)(bufc + ((unsigned)(((mf * 16 + l15) << 7) + ((lq * 8) << 1)) ^ rsw));
        SCHED0();
        w2b[0] = ldw2(h, kt, 1, 0); w2b[1] = ldw2(h, kt, 1, 1);
        WAITVL(6);                         // w2a (kb0) ready
        __builtin_amdgcn_s_setprio(1);
#pragma unroll
        for (int nf = 0; nf < 2; nf++)
#pragma unroll
          for (int mf = 0; mf < 8; mf++)
            c2[nf][mf] = MFMA16(w2a[nf], a1f[mf], c2[nf][mf]);
        __builtin_amdgcn_s_setprio(0);
      }
      { // kb1
        v8s a1f[8];
#pragma unroll
        for (int mf = 0; mf < 8; mf++)
          a1f[mf] = *(const v8s*)(bufc + ((unsigned)(((mf * 16 + l15) << 7) + ((32 + lq * 8) << 1)) ^ rsw));
        SCHED0();
        const int s2 = (s + 1) & 15;
        w2a[0] = ldw2(s2 >> 3, s2 & 7, 0, 0); w2a[1] = ldw2(s2 >> 3, s2 & 7, 0, 1);
        WAITVL(2);                         // w2b (kb1) ready
        __builtin_amdgcn_s_setprio(1);
#pragma unroll
        for (int nf = 0; nf < 2; nf++)
#pragma unroll
          for (int mf = 0; mf < 8; mf++)
            c2[nf][mf] = MFMA16(w2b[nf], a1f[mf], c2[nf][mf]);
        __builtin_amdgcn_s_setprio(0);
      }
      BARRIER();
      if (s == 7){
        // A2 = relu(c2+b2) for n-pass 0 -> sA2 ; re-zero c2
#pragma unroll
        for (int nf = 0; nf < 2; nf++){
          const int nb = 0 * 256 + w * 32 + nf * 16 + (lq << 2);
          const float4 bb = *(const float4*)(b2 + nb);
#pragma unroll
          for (int mf = 0; mf < 8; mf++){
            v4f vv = c2[nf][mf];
            unsigned lo = (unsigned)f2bf(fmaxf(vv[0] + bb.x, 0.f)) | ((unsigned)f2bf(fmaxf(vv[1] + bb.y, 0.f)) << 16);
            unsigned hi = (unsigned)f2bf(fmaxf(vv[2] + bb.z, 0.f)) | ((unsigned)f2bf(fmaxf(vv[3] + bb.w, 0.f)) << 16);
            const int m = mf * 16 + l15;
            *(uint2*)(sA2 + ((unsigned)((m << 10) + (nb << 1)) ^ rsw)) = make_uint2(lo, hi);
            c2[nf][mf] = (v4f){0.f, 0.f, 0.f, 0.f};
          }
        }
      }
    }
    // A2 pass 1
#pragma unroll
    for (int nf = 0; nf < 2; nf++){
      const int nb = 256 + w * 32 + nf * 16 + (lq << 2);
      const float4 bb = *(const float4*)(b2 + nb);
#pragma unroll
      for (int mf = 0; mf < 8; mf++){
        v4f vv = c2[nf][mf];
        unsigned lo = (unsigned)f2bf(fmaxf(vv[0] + bb.x, 0.f)) | ((unsigned)f2bf(fmaxf(vv[1] + bb.y, 0.f)) << 16);
        unsigned hi = (unsigned)f2bf(fmaxf(vv[2] + bb.z, 0.f)) | ((unsigned)f2bf(fmaxf(vv[3] + bb.w, 0.f)) << 16);
        const int m = mf * 16 + l15;
        *(uint2*)(sA2 + ((unsigned)((m << 10) + (nb << 1)) ^ rsw)) = make_uint2(lo, hi);
        c2[nf][mf] = (v4f){0.f, 0.f, 0.f, 0.f};
      }
    }
    BARRIER();                             // sA2 fully visible

    // ---- GEMM3: barrier-free, w3 ping-pong, c3 per j ----
    v4f c3[8][2];
#pragma unroll
    for (int mf = 0; mf < 8; mf++)
#pragma unroll
      for (int nf = 0; nf < 2; nf++) c3[mf][nf] = (v4f){0.f, 0.f, 0.f, 0.f};
    v8s w3r[2][2];
    w3r[0][0] = ldw3(0, 0); w3r[0][1] = ldw3(0, 1);
    SCHED0();
#pragma unroll
    for (int it = 0; it < 16; ++it){
      v8s a2f[8];
#pragma unroll
      for (int mf = 0; mf < 8; mf++){
        const int row = mf * 16 + l15;
        a2f[mf] = *(const v8s*)(sA2 + ((unsigned)((row << 10) + ((it * 32 + lq * 8) << 1)) ^ rsw));
      }
      SCHED0();
      const int itn = (it + 1) & 15;
      w3r[(it + 1) & 1][0] = ldw3(itn, 0); w3r[(it + 1) & 1][1] = ldw3(itn, 1);
      WAITVL(2);                           // w3r[it&1] ready
      __builtin_amdgcn_s_setprio(1);
#pragma unroll
      for (int mf = 0; mf < 8; mf++)
#pragma unroll
        for (int nf = 0; nf < 2; nf++)
          c3[mf][nf] = MFMA16(a2f[mf], w3r[it & 1][nf], c3[mf][nf]);
      __builtin_amdgcn_s_setprio(0);
    }
#pragma unroll
    for (int mf = 0; mf < 8; mf++)
#pragma unroll
      for (int e = 0; e < 4; e++){
        acc[mf][0][e] += fmaxf(c3[mf][0][e] + b3v0, 0.f);
        acc[mf][1][e] += fmaxf(c3[mf][1][e] + b3v1, 0.f);
      }

    Vc = Vn;
  }

  // ---- epilogue: f32 partial slab (plain stores) ----
  float* pp = Pp + (((size_t)(i * 4 + jg)) << 17) + ((size_t)b0 << 8) + (w * 32) + l15;
#pragma unroll
  for (int mf = 0; mf < 8; mf++)
#pragma unroll
    for (int nf = 0; nf < 2; nf++)
#pragma unroll
      for (int e = 0; e < 4; e++)
        pp[(size_t)((mf * 16 + (lq << 2) + e) << 8) + nf * 16] = acc[mf][nf][e];
}

// ---------- slab reduction: out += sum of 4 jg-slabs per i ----------
__global__ __launch_bounds__(256) void k_reduce(const float* __restrict__ Pp,
                                                float* __restrict__ out){
  int idx = blockIdx.x * 256 + threadIdx.x;     // one thread per 4 cols
  const int c4  = (idx & 63) << 2;
  const int row = idx >> 6;                     // 0..8191
  const int i   = row >> 9;
  const float* pb = Pp + (((size_t)(i * 4)) << 17) + (((size_t)(row & 511)) << 8) + c4;
  float4 s0 = *(const float4*)(pb);
  float4 s1 = *(const float4*)(pb + (1 << 17));
  float4 s2 = *(const float4*)(pb + (2 << 17));
  float4 s3 = *(const float4*)(pb + (3 << 17));
  float4* op = (float4*)(out + ((size_t)row << 8) + c4);
  float4 o = *op;
  o.x += s0.x + s1.x + s2.x + s3.x;
  o.y += s0.y + s1.y + s2.y + s3.y;
  o.z += s0.z + s1.z + s2.z + s3.z;
  o.w += s0.w + s1.w + s2.w + s3.w;
  *op = o;
}

// ---------- host ----------

extern "C" void kernel_launch(void* const* d_in, const int* in_sizes, int n_in,
                              void* d_out, int out_size, void* d_ws, size_t ws_size,
                              hipStream_t stream){
  const float* objs = (const float*)d_in[0];
  const float* tW1  = (const float*)d_in[1];
  const float* tb1  = (const float*)d_in[2];
  const float* tW2  = (const float*)d_in[3];
  const float* tb2  = (const float*)d_in[4];
  const float* tW3  = (const float*)d_in[5];
  const float* tb3  = (const float*)d_in[6];
  const float* iW1  = (const float*)d_in[7];
  const float* ib1  = (const float*)d_in[8];
  const float* iW2  = (const float*)d_in[9];
  const float* ib2  = (const float*)d_in[10];
  const float* iW3  = (const float*)d_in[11];
  const float* ib3  = (const float*)d_in[12];

  char* ws = (char*)d_ws;
  size_t off = 0;
  unsigned short* objsb = (unsigned short*)(ws + off); off += (size_t)RR * DD * 2;        // 4 MB
  unsigned short* H1    = (unsigned short*)(ws + off); off += (size_t)RR * 512 * 2;       // 8 MB
  unsigned short* H2    = (unsigned short*)(ws + off); off += (size_t)RR * 512 * 2;       // 8 MB
  unsigned short* UVb   = (unsigned short*)(ws + off); off += (size_t)RR * 1024 * 2;      // 16 MB
  unsigned short* Wcat  = (unsigned short*)(ws + off); off += 1536 * 256 * 2;
  unsigned short* tW2t  = (unsigned short*)(ws + off); off += 512 * 512 * 2;
  unsigned short* tW3t  = (unsigned short*)(ws + off); off += 256 * 512 * 2;
  unsigned short* iW2t  = (unsigned short*)(ws + off); off += 512 * 512 * 2;
  unsigned short* iW3t  = (unsigned short*)(ws + off); off += 256 * 512 * 2;
  float*          bcat  = (float*)(ws + off);          off += 1536 * 4;
  float*          Pp    = (float*)(ws + off);          off += (size_t)64 * 512 * 256 * 4; // 33.5 MB
  (void)ws_size; (void)in_sizes; (void)n_in; (void)out_size;

  // prep
  k_cast4<<<dim3((RR * DD / 4 + 255) / 256), dim3(256), 0, stream>>>(objs, objsb, RR * DD / 4);
  k_prep<<<dim3(4614), dim3(256), 0, stream>>>(tW1, tW2, tW3, iW1, iW2, iW3, tb1, ib1,
                                               Wcat, tW2t, tW3t, iW2t, iW3t, bcat);

  // merged H1 + UV GEMM (split epilogue)
  k_gemm<256, true, false, false, true ><<<dim3(RR / 64, 12), dim3(256), 0, stream>>>(
      objsb, Wcat, bcat, H1, nullptr, UVb, RR, 1536);
  // H2 = relu(H1@tW2+tb2)
  k_gemm<512, true, true,  false, false><<<dim3(RR / 64, 4), dim3(256), 0, stream>>>(
      H1, tW2t, tb2, H2, nullptr, nullptr, RR, 512);
  // T path: out = relu(H2@tW3+tb3) + objs
  k_gemm<512, false, true, true,  false><<<dim3(RR / 64, 2), dim3(256), 0, stream>>>(
      H2, tW3t, tb3, d_out, objs, nullptr, RR, DD);

  // fused pair interaction -> f32 partial slabs
  k_pair3<<<dim3(256), dim3(512), 0, stream>>>(UVb, iW2t, iW3t, ib2, ib3, Pp);

  // out += sum of 4 slabs per i
  k_reduce<<<dim3(2048), dim3(256), 0, stream>>>(Pp, (float*)d_out);
}

// Round 5
// 365.999 us; speedup vs baseline: 1.3236x; 1.3236x over previous
//
#include <hip/hip_runtime.h>

#define NN 16
#define BB 512
#define DD 256
#define RR (NN*BB)   // 8192

typedef __attribute__((ext_vector_type(8))) short v8s;
typedef __attribute__((ext_vector_type(4))) float v4f;

#define MFMA16(a,b,c) __builtin_amdgcn_mfma_f32_16x16x32_bf16((a),(b),(c),0,0,0)

__device__ __forceinline__ unsigned short f2bf(float f){
  unsigned int x = __float_as_uint(f);
  x += 0x7fffu + ((x >> 16) & 1u);
  return (unsigned short)(x >> 16);
}
__device__ __forceinline__ float bf2f(unsigned short u){
  return __uint_as_float(((unsigned int)u) << 16);
}

// ---------- prep kernels ----------

__global__ __launch_bounds__(256) void k_cast4(const float* __restrict__ in,
                                               unsigned short* __restrict__ out, int n4){
  int idx = blockIdx.x * 256 + threadIdx.x;
  if (idx < n4){
    float4 v = ((const float4*)in)[idx];
    ushort4 o;
    o.x = f2bf(v.x); o.y = f2bf(v.y); o.z = f2bf(v.z); o.w = f2bf(v.w);
    ((ushort4*)out)[idx] = o;
  }
}

// all weight transposes + iW1 split + ib1ext in ONE launch (segment dispatch)
__global__ __launch_bounds__(256) void k_prep(
    const float* __restrict__ tW1, const float* __restrict__ tW2, const float* __restrict__ tW3,
    const float* __restrict__ iW1, const float* __restrict__ iW2, const float* __restrict__ iW3,
    const float* __restrict__ ib1,
    unsigned short* __restrict__ tW1t, unsigned short* __restrict__ tW2t, unsigned short* __restrict__ tW3t,
    unsigned short* __restrict__ iW1abt, unsigned short* __restrict__ iW2t, unsigned short* __restrict__ iW3t,
    float* __restrict__ ib1ext){
  int idx = blockIdx.x * 256 + threadIdx.x;
  if (idx < 131072){                                   // tW1t [512][256] <- tW1 [256][512]
    int n = idx >> 8, k = idx & 255;
    tW1t[idx] = f2bf(tW1[k * 512 + n]);
    return;
  }
  idx -= 131072;
  if (idx < 262144){                                   // tW2t [512][512]
    int n = idx >> 9, k = idx & 511;
    tW2t[idx] = f2bf(tW2[k * 512 + n]);
    return;
  }
  idx -= 262144;
  if (idx < 131072){                                   // tW3t [256][512] <- tW3 [512][256]
    int n = idx >> 9, k = idx & 511;
    tW3t[idx] = f2bf(tW3[k * 256 + n]);
    return;
  }
  idx -= 131072;
  if (idx < 262144){                                   // iW2t [512][512]
    int n = idx >> 9, k = idx & 511;
    iW2t[idx] = f2bf(iW2[k * 512 + n]);
    return;
  }
  idx -= 262144;
  if (idx < 131072){                                   // iW3t [256][512]
    int n = idx >> 9, k = idx & 511;
    iW3t[idx] = f2bf(iW3[k * 256 + n]);
    return;
  }
  idx -= 131072;
  if (idx < 262144){                                   // iW1abt [1024][256]
    int r = idx >> 8, k = idx & 255;
    float v = (r < 512) ? iW1[k * 512 + r] : iW1[(k + 256) * 512 + (r - 512)];
    iW1abt[idx] = f2bf(v);
    return;
  }
  idx -= 262144;
  if (idx < 1024)                                      // ib1ext: [0 | ib1]
    ib1ext[idx] = (idx < 512) ? 0.f : ib1[idx - 512];
}

// ---------- phase-A GEMM ----------
// C[M][Nn] = act(A[M][KD] @ Wt[Nn][KD]^T + bias) (+ extra)
template<int KD, bool OUTBF16, bool RELU, bool ADDX>
__global__ __launch_bounds__(256) void k_gemm(const unsigned short* __restrict__ A,
                                              const unsigned short* __restrict__ Wt,
                                              const float* __restrict__ bias,
                                              void* __restrict__ Cout,
                                              const float* __restrict__ extra,
                                              int M, int Nn){
  __shared__ __align__(16) unsigned char sA[64 * 128];
  __shared__ __align__(16) unsigned char sB[128 * 128];
  const int m0 = blockIdx.x * 64;
  const int n0 = blockIdx.y * 128;
  const int t = threadIdx.x;
  const int w = t >> 6, l = t & 63;
  const int l15 = l & 15, lq = l >> 4;
  const int rowh = (w & 1) * 32, colh = (w >> 1) * 64;

  v4f c[2][4];
#pragma unroll
  for (int r = 0; r < 2; r++)
#pragma unroll
    for (int q = 0; q < 4; q++) c[r][q] = (v4f){0.f, 0.f, 0.f, 0.f};

  for (int kt = 0; kt < KD; kt += 64){
    __syncthreads();
    {
      const int row = t >> 2, cq = (t & 3) * 16;
      const unsigned short* src = A + (size_t)(m0 + row) * KD + kt + cq;
      v8s a0 = *(const v8s*)(src);
      v8s a1 = *(const v8s*)(src + 8);
      const unsigned sw = (unsigned)((row & 7) << 4);
      *(v8s*)(sA + ((unsigned)((row << 7) + (cq << 1)) ^ sw)) = a0;
      *(v8s*)(sA + ((unsigned)((row << 7) + (cq << 1) + 16) ^ sw)) = a1;
    }
    {
      const int n = t & 127, kq = (t >> 7) * 32;
      const unsigned short* src = Wt + (size_t)(n0 + n) * KD + kt + kq;
      const unsigned base = (unsigned)((n << 7) + (kq << 1));
      const unsigned sw = (unsigned)((n & 7) << 4);
#pragma unroll
      for (int q = 0; q < 4; q++){
        v8s v = *(const v8s*)(src + q * 8);
        *(v8s*)(sB + ((base + q * 16) ^ sw)) = v;
      }
    }
    __syncthreads();
#pragma unroll
    for (int kb = 0; kb < 64; kb += 32){
      v8s af[2], bfr[4];
#pragma unroll
      for (int r = 0; r < 2; r++){
        const int row = rowh + r * 16 + l15;
        af[r] = *(const v8s*)(sA + ((unsigned)((row << 7) + ((kb + (lq << 3)) << 1)) ^ (unsigned)((row & 7) << 4)));
      }
#pragma unroll
      for (int q = 0; q < 4; q++){
        const int n = colh + q * 16 + l15;
        bfr[q] = *(const v8s*)(sB + ((unsigned)((n << 7) + ((kb + (lq << 3)) << 1)) ^ (unsigned)((n & 7) << 4)));
      }
#pragma unroll
      for (int r = 0; r < 2; r++)
#pragma unroll
        for (int q = 0; q < 4; q++)
          c[r][q] = MFMA16(af[r], bfr[q], c[r][q]);
    }
  }
#pragma unroll
  for (int r = 0; r < 2; r++){
#pragma unroll
    for (int q = 0; q < 4; q++){
      const int col = n0 + colh + q * 16 + l15;
      const float bv = bias ? bias[col] : 0.0f;
#pragma unroll
      for (int e = 0; e < 4; e++){
        const int row = m0 + rowh + r * 16 + (lq << 2) + e;
        float v = c[r][q][e] + bv;
        if (RELU) v = fmaxf(v, 0.0f);
        if (ADDX) v += extra[(size_t)row * Nn + col];
        if (OUTBF16) ((unsigned short*)Cout)[(size_t)row * Nn + col] = f2bf(v);
        else         ((float*)Cout)[(size_t)row * Nn + col] = v;
      }
    }
  }
}

// ---------- fused pair kernel v4: 64-row tile, 2 WGs/CU ----------
// One WG = one (i,j) pair x 64 batch rows. 512 threads (8 waves), 72 KB LDS
// -> 2 WGs/CU co-resident (4 waves/SIMD): cross-WG overlap hides barriers
// and W2/W3 L2 latency. Simple __syncthreads structure (compiler schedules).
// GEMM2: 8 waves x 64 n-cols, swapped mfma so A2 packs [m][k] contiguously.
// GEMM3: barrier-free, wave grid 2m x 4n.
// Epilogue: bf16 partial slab P[pair][512][256]; k_reduce sums 15 per i.
__global__ __launch_bounds__(512, 4) void k_pair4(
    const unsigned short* __restrict__ UV,   // [8192][1024] bf16: U' | V'+ib1
    const unsigned short* __restrict__ W2t,  // [512][512] bf16 (n,k)
    const unsigned short* __restrict__ W3t,  // [256][512] bf16 (n,k)
    const float* __restrict__ b2,
    const float* __restrict__ b3,
    unsigned short* __restrict__ P){         // [240][512][256] bf16 partials
  __shared__ __align__(16) unsigned char sA1[64 * 128];   // 8 KB  [64 m][64 k]
  __shared__ __align__(16) unsigned char sA2[64 * 1024];  // 64 KB [64 m][512 k]

  // XCD swizzle: 1920 WGs = 8 XCDs x 240 (pairs i-major within each chunk)
  const int bid = blockIdx.x;
  const int wg  = (bid & 7) * 240 + (bid >> 3);
  const int p   = wg >> 3;               // pair 0..239
  const int e8  = wg & 7;                // 64-row eighth
  const int i   = p / 15;
  const int rj  = p - i * 15;
  const int j   = rj + (rj >= i ? 1 : 0);
  const int b0  = e8 * 64;

  const int t = threadIdx.x;
  const int w = t >> 6, l = t & 63, l15 = l & 15, lq = l >> 4;
  const int n0w = w * 64;

  // staging map: 512 threads -> 64 rows x 64 k (8 threads/row, 8 k each)
  const int sr = t >> 3, sk = (t & 7) << 3;
  const unsigned short* Up = UV + ((size_t)(i * BB + b0 + sr) << 10) + sk;
  const unsigned short* Vp = UV + ((size_t)(j * BB + b0 + sr) << 10) + 512 + sk;
  const unsigned a1w = ((unsigned)((sr << 7) + (sk << 1))) ^ ((unsigned)((sr & 7) << 4));

  v8s u0 = *(const v8s*)(Up);
  v8s v0 = *(const v8s*)(Vp);

  v4f c2[4][4];
#pragma unroll
  for (int nf = 0; nf < 4; nf++)
#pragma unroll
    for (int mf = 0; mf < 4; mf++) c2[nf][mf] = (v4f){0.f, 0.f, 0.f, 0.f};

  for (int kt = 0; kt < 512; kt += 64){
    if (kt) __syncthreads();
    { // convert staged regs -> sA1
      v8s p0;
#pragma unroll
      for (int e = 0; e < 8; e++)
        p0[e] = (short)f2bf(fmaxf(bf2f((unsigned short)u0[e]) + bf2f((unsigned short)v0[e]), 0.f));
      *(v8s*)(sA1 + a1w) = p0;
    }
    __syncthreads();
    if (kt < 448){                       // prefetch next tile
      u0 = *(const v8s*)(Up + kt + 64);
      v0 = *(const v8s*)(Vp + kt + 64);
    }
#pragma unroll
    for (int kb = 0; kb < 64; kb += 32){
      v8s a1f[4], w2f[4];
#pragma unroll
      for (int nf = 0; nf < 4; nf++)
        w2f[nf] = *(const v8s*)(W2t + (((size_t)(n0w + nf * 16 + l15)) << 9) + kt + kb + (lq << 3));
#pragma unroll
      for (int mf = 0; mf < 4; mf++){
        const int row = mf * 16 + l15;
        a1f[mf] = *(const v8s*)(sA1 + ((unsigned)((row << 7) + ((kb + (lq << 3)) << 1)) ^ (unsigned)((row & 7) << 4)));
      }
      __builtin_amdgcn_s_setprio(1);
#pragma unroll
      for (int nf = 0; nf < 4; nf++)
#pragma unroll
        for (int mf = 0; mf < 4; mf++)
          c2[nf][mf] = MFMA16(w2f[nf], a1f[mf], c2[nf][mf]);
      __builtin_amdgcn_s_setprio(0);
    }
  }

  // A2 = relu(c2 + b2) -> sA2 [m][k] packed b64 (e-axis contiguous n = GEMM3 k)
#pragma unroll
  for (int nf = 0; nf < 4; nf++){
    const float4 bb = *(const float4*)(b2 + n0w + nf * 16 + (lq << 2));
#pragma unroll
    for (int mf = 0; mf < 4; mf++){
      v4f vv = c2[nf][mf];
      unsigned lo = (unsigned)f2bf(fmaxf(vv[0] + bb.x, 0.f)) | ((unsigned)f2bf(fmaxf(vv[1] + bb.y, 0.f)) << 16);
      unsigned hi = (unsigned)f2bf(fmaxf(vv[2] + bb.z, 0.f)) | ((unsigned)f2bf(fmaxf(vv[3] + bb.w, 0.f)) << 16);
      const int row = mf * 16 + l15;
      const unsigned addr = (unsigned)((row << 10) + ((n0w + nf * 16 + (lq << 2)) << 1)) ^ (unsigned)((row & 7) << 4);
      *(uint2*)(sA2 + addr) = make_uint2(lo, hi);
    }
  }
  __syncthreads();

  // GEMM3: barrier-free. wave grid 2m x 4n: rows wm*32.., cols wn*64..
  const int wm = w & 1, wn = w >> 1;
  v4f c3[2][4];
#pragma unroll
  for (int mf = 0; mf < 2; mf++)
#pragma unroll
    for (int nf = 0; nf < 4; nf++) c3[mf][nf] = (v4f){0.f, 0.f, 0.f, 0.f};

#pragma unroll 2
  for (int kb3 = 0; kb3 < 512; kb3 += 32){
    v8s a2f[2], w3f[4];
#pragma unroll
    for (int nf = 0; nf < 4; nf++)
      w3f[nf] = *(const v8s*)(W3t + (((size_t)(wn * 64 + nf * 16 + l15)) << 9) + kb3 + (lq << 3));
#pragma unroll
    for (int mf = 0; mf < 2; mf++){
      const int row = wm * 32 + mf * 16 + l15;
      a2f[mf] = *(const v8s*)(sA2 + ((unsigned)((row << 10) + ((kb3 + (lq << 3)) << 1)) ^ (unsigned)((row & 7) << 4)));
    }
    __builtin_amdgcn_s_setprio(1);
#pragma unroll
    for (int mf = 0; mf < 2; mf++)
#pragma unroll
      for (int nf = 0; nf < 4; nf++)
        c3[mf][nf] = MFMA16(a2f[mf], w3f[nf], c3[mf][nf]);
    __builtin_amdgcn_s_setprio(0);
  }

  // epilogue: plain bf16 stores into pair slab
  unsigned short* pb = P + ((size_t)p << 17) + (((size_t)(b0 + wm * 32)) << 8);
#pragma unroll
  for (int nf = 0; nf < 4; nf++){
    const int col = wn * 64 + nf * 16 + l15;
    const float b3v = b3[col];
#pragma unroll
    for (int mf = 0; mf < 2; mf++){
#pragma unroll
      for (int e = 0; e < 4; e++){
        const int row = mf * 16 + (lq << 2) + e;
        pb[((size_t)row << 8) + col] = f2bf(fmaxf(c3[mf][nf][e] + b3v, 0.f));
      }
    }
  }
}

// ---------- slab reduction: out += sum_{15 slabs of i} P ----------
__global__ __launch_bounds__(256) void k_reduce(const unsigned short* __restrict__ P,
                                                float* __restrict__ out){
  int idx = blockIdx.x * 256 + threadIdx.x;     // one thread per 4 cols
  const int c4  = (idx & 63) << 2;
  const int row = idx >> 6;                     // 0..8191
  const int i   = row >> 9;
  const unsigned short* pb = P + (((size_t)(i * 15)) << 17) + (((size_t)(row & 511)) << 8) + c4;
  float s0 = 0.f, s1 = 0.f, s2 = 0.f, s3 = 0.f;
#pragma unroll
  for (int s = 0; s < 15; s++){
    ushort4 v = *(const ushort4*)(pb + ((size_t)s << 17));
    s0 += bf2f(v.x); s1 += bf2f(v.y); s2 += bf2f(v.z); s3 += bf2f(v.w);
  }
  float4* op = (float4*)(out + ((size_t)row << 8) + c4);
  float4 o = *op;
  o.x += s0; o.y += s1; o.z += s2; o.w += s3;
  *op = o;
}

// ---------- host ----------

extern "C" void kernel_launch(void* const* d_in, const int* in_sizes, int n_in,
                              void* d_out, int out_size, void* d_ws, size_t ws_size,
                              hipStream_t stream){
  const float* objs = (const float*)d_in[0];
  const float* tW1  = (const float*)d_in[1];
  const float* tb1  = (const float*)d_in[2];
  const float* tW2  = (const float*)d_in[3];
  const float* tb2  = (const float*)d_in[4];
  const float* tW3  = (const float*)d_in[5];
  const float* tb3  = (const float*)d_in[6];
  const float* iW1  = (const float*)d_in[7];
  const float* ib1  = (const float*)d_in[8];
  const float* iW2  = (const float*)d_in[9];
  const float* ib2  = (const float*)d_in[10];
  const float* iW3  = (const float*)d_in[11];
  const float* ib3  = (const float*)d_in[12];
  float* out = (float*)d_out;

  char* ws = (char*)d_ws;
  size_t off = 0;
  unsigned short* objsb  = (unsigned short*)(ws + off); off += (size_t)RR * DD * 2;        // 4 MB
  unsigned short* H1     = (unsigned short*)(ws + off); off += (size_t)RR * 512 * 2;       // 8 MB
  unsigned short* H2     = (unsigned short*)(ws + off); off += (size_t)RR * 512 * 2;       // 8 MB
  unsigned short* UVb    = (unsigned short*)(ws + off); off += (size_t)RR * 1024 * 2;      // 16 MB
  unsigned short* tW1t   = (unsigned short*)(ws + off); off += 512 * 256 * 2;
  unsigned short* tW2t   = (unsigned short*)(ws + off); off += 512 * 512 * 2;
  unsigned short* tW3t   = (unsigned short*)(ws + off); off += 256 * 512 * 2;
  unsigned short* iW1abt = (unsigned short*)(ws + off); off += 1024 * 256 * 2;
  unsigned short* iW2t   = (unsigned short*)(ws + off); off += 512 * 512 * 2;
  unsigned short* iW3t   = (unsigned short*)(ws + off); off += 256 * 512 * 2;
  float*          ib1ext = (float*)(ws + off);          off += 1024 * 4;
  unsigned short* P      = (unsigned short*)(ws + off); off += (size_t)240 * 512 * 256 * 2; // 60 MB
  (void)ws_size; (void)in_sizes; (void)n_in; (void)out_size;

  // prep: cast objs + all weight transposes (2 launches)
  k_cast4<<<dim3((RR * DD / 4 + 255) / 256), dim3(256), 0, stream>>>(objs, objsb, RR * DD / 4);
  k_prep<<<dim3(4609), dim3(256), 0, stream>>>(tW1, tW2, tW3, iW1, iW2, iW3, ib1,
                                               tW1t, tW2t, tW3t, iW1abt, iW2t, iW3t, ib1ext);

  // phase-A GEMMs
  k_gemm<256, true,  true,  false><<<dim3(RR / 64, 4), dim3(256), 0, stream>>>(objsb, tW1t, tb1, H1, nullptr, RR, 512);
  k_gemm<256, true,  false, false><<<dim3(RR / 64, 8), dim3(256), 0, stream>>>(objsb, iW1abt, ib1ext, UVb, nullptr, RR, 1024);
  k_gemm<512, true,  true,  false><<<dim3(RR / 64, 4), dim3(256), 0, stream>>>(H1, tW2t, tb2, H2, nullptr, RR, 512);
  // T path: out = relu(H2@tW3+tb3) + objs
  k_gemm<512, false, true,  true ><<<dim3(RR / 64, 2), dim3(256), 0, stream>>>(H2, tW3t, tb3, d_out, objs, RR, DD);

  // fused pair interaction -> bf16 partial slabs (no atomics)
  k_pair4<<<dim3(1920), dim3(512), 0, stream>>>(UVb, iW2t, iW3t, ib2, ib3, P);

  // out += sum of 15 slabs per i
  k_reduce<<<dim3(2048), dim3(256), 0, stream>>>(P, out);
}

// Round 6
// 264.817 us; speedup vs baseline: 1.8293x; 1.3821x over previous
//
#include <hip/hip_runtime.h>

#define NN 16
#define BB 512
#define DD 256
#define RR (NN*BB)   // 8192

typedef __attribute__((ext_vector_type(8))) short v8s;
typedef __attribute__((ext_vector_type(4))) float v4f;

#define MFMA16(a,b,c) __builtin_amdgcn_mfma_f32_16x16x32_bf16((a),(b),(c),0,0,0)

__device__ __forceinline__ unsigned short f2bf(float f){
  unsigned int x = __float_as_uint(f);
  x += 0x7fffu + ((x >> 16) & 1u);
  return (unsigned short)(x >> 16);
}
__device__ __forceinline__ float bf2f(unsigned short u){
  return __uint_as_float(((unsigned int)u) << 16);
}
// packed f32x2 -> bf16x2 (S0 -> low16, S1 -> high16), RTNE — same as f2bf
__device__ __forceinline__ unsigned cvt_pk(float lo, float hi){
  unsigned r;
  asm("v_cvt_pk_bf16_f32 %0, %1, %2" : "=v"(r) : "v"(lo), "v"(hi));
  return r;
}

// ---------- prep kernels ----------

__global__ __launch_bounds__(256) void k_cast4(const float* __restrict__ in,
                                               unsigned short* __restrict__ out, int n4){
  int idx = blockIdx.x * 256 + threadIdx.x;
  if (idx < n4){
    float4 v = ((const float4*)in)[idx];
    ushort4 o;
    o.x = f2bf(v.x); o.y = f2bf(v.y); o.z = f2bf(v.z); o.w = f2bf(v.w);
    ((ushort4*)out)[idx] = o;
  }
}

// weight transposes + concat + bias concat in one launch
// Wcat [1536][256]: rows 0..511 = tW1^T ; 512..1023 = iW1-top^T ; 1024..1535 = iW1-bot^T
// bcat [1536] = [tb1 | 0 | ib1]
__global__ __launch_bounds__(256) void k_prep(
    const float* __restrict__ tW1, const float* __restrict__ tW2, const float* __restrict__ tW3,
    const float* __restrict__ iW1, const float* __restrict__ iW2, const float* __restrict__ iW3,
    const float* __restrict__ tb1, const float* __restrict__ ib1,
    unsigned short* __restrict__ Wcat, unsigned short* __restrict__ tW2t, unsigned short* __restrict__ tW3t,
    unsigned short* __restrict__ iW2t, unsigned short* __restrict__ iW3t,
    float* __restrict__ bcat){
  int idx = blockIdx.x * 256 + threadIdx.x;
  if (idx < 131072){                                   // Wcat rows 0..511 <- tW1 [256][512]
    int n = idx >> 8, k = idx & 255;
    Wcat[idx] = f2bf(tW1[k * 512 + n]);
    return;
  }
  idx -= 131072;
  if (idx < 262144){                                   // tW2t [512][512]
    int n = idx >> 9, k = idx & 511;
    tW2t[idx] = f2bf(tW2[k * 512 + n]);
    return;
  }
  idx -= 262144;
  if (idx < 131072){                                   // tW3t [256][512] <- tW3 [512][256]
    int n = idx >> 9, k = idx & 511;
    tW3t[idx] = f2bf(tW3[k * 256 + n]);
    return;
  }
  idx -= 131072;
  if (idx < 262144){                                   // iW2t [512][512]
    int n = idx >> 9, k = idx & 511;
    iW2t[idx] = f2bf(iW2[k * 512 + n]);
    return;
  }
  idx -= 262144;
  if (idx < 131072){                                   // iW3t [256][512]
    int n = idx >> 9, k = idx & 511;
    iW3t[idx] = f2bf(iW3[k * 256 + n]);
    return;
  }
  idx -= 131072;
  if (idx < 262144){                                   // Wcat rows 512..1535 <- iW1 split
    int r = idx >> 8, k = idx & 255;
    float v = (r < 512) ? iW1[k * 512 + r] : iW1[(k + 256) * 512 + (r - 512)];
    Wcat[(512 << 8) + idx] = f2bf(v);
    return;
  }
  idx -= 262144;
  if (idx < 1536)
    bcat[idx] = (idx < 512) ? tb1[idx] : ((idx < 1024) ? 0.f : ib1[idx - 1024]);
}

// ---------- phase-A GEMM ----------
// C[M][Nn] = act(A[M][KD] @ Wt[Nn][KD]^T + bias) (+ extra); SPLIT: H1(relu)/UV(bias)
template<int KD, bool OUTBF16, bool RELU, bool ADDX, bool SPLIT>
__global__ __launch_bounds__(256) void k_gemm(const unsigned short* __restrict__ A,
                                              const unsigned short* __restrict__ Wt,
                                              const float* __restrict__ bias,
                                              void* __restrict__ Cout,
                                              const float* __restrict__ extra,
                                              void* __restrict__ Cout2,
                                              int M, int Nn){
  __shared__ __align__(16) unsigned char sA[64 * 128];
  __shared__ __align__(16) unsigned char sB[128 * 128];
  const int m0 = blockIdx.x * 64;
  const int n0 = blockIdx.y * 128;
  const int t = threadIdx.x;
  const int w = t >> 6, l = t & 63;
  const int l15 = l & 15, lq = l >> 4;
  const int rowh = (w & 1) * 32, colh = (w >> 1) * 64;

  v4f c[2][4];
#pragma unroll
  for (int r = 0; r < 2; r++)
#pragma unroll
    for (int q = 0; q < 4; q++) c[r][q] = (v4f){0.f, 0.f, 0.f, 0.f};

  for (int kt = 0; kt < KD; kt += 64){
    __syncthreads();
    {
      const int row = t >> 2, cq = (t & 3) * 16;
      const unsigned short* src = A + (size_t)(m0 + row) * KD + kt + cq;
      v8s a0 = *(const v8s*)(src);
      v8s a1 = *(const v8s*)(src + 8);
      const unsigned sw = (unsigned)((row & 7) << 4);
      *(v8s*)(sA + ((unsigned)((row << 7) + (cq << 1)) ^ sw)) = a0;
      *(v8s*)(sA + ((unsigned)((row << 7) + (cq << 1) + 16) ^ sw)) = a1;
    }
    {
      const int n = t & 127, kq = (t >> 7) * 32;
      const unsigned short* src = Wt + (size_t)(n0 + n) * KD + kt + kq;
      const unsigned base = (unsigned)((n << 7) + (kq << 1));
      const unsigned sw = (unsigned)((n & 7) << 4);
#pragma unroll
      for (int q = 0; q < 4; q++){
        v8s v = *(const v8s*)(src + q * 8);
        *(v8s*)(sB + ((base + q * 16) ^ sw)) = v;
      }
    }
    __syncthreads();
#pragma unroll
    for (int kb = 0; kb < 64; kb += 32){
      v8s af[2], bfr[4];
#pragma unroll
      for (int r = 0; r < 2; r++){
        const int row = rowh + r * 16 + l15;
        af[r] = *(const v8s*)(sA + ((unsigned)((row << 7) + ((kb + (lq << 3)) << 1)) ^ (unsigned)((row & 7) << 4)));
      }
#pragma unroll
      for (int q = 0; q < 4; q++){
        const int n = colh + q * 16 + l15;
        bfr[q] = *(const v8s*)(sB + ((unsigned)((n << 7) + ((kb + (lq << 3)) << 1)) ^ (unsigned)((n & 7) << 4)));
      }
#pragma unroll
      for (int r = 0; r < 2; r++)
#pragma unroll
        for (int q = 0; q < 4; q++)
          c[r][q] = MFMA16(af[r], bfr[q], c[r][q]);
    }
  }
#pragma unroll
  for (int r = 0; r < 2; r++){
#pragma unroll
    for (int q = 0; q < 4; q++){
      const int col = n0 + colh + q * 16 + l15;
      const float bv = bias ? bias[col] : 0.0f;
#pragma unroll
      for (int e = 0; e < 4; e++){
        const int row = m0 + rowh + r * 16 + (lq << 2) + e;
        float v = c[r][q][e] + bv;
        if (SPLIT){
          if (col < 512){
            ((unsigned short*)Cout)[(size_t)row * 512 + col] = f2bf(fmaxf(v, 0.0f));
          } else {
            ((unsigned short*)Cout2)[(size_t)row * 1024 + (col - 512)] = f2bf(v);
          }
        } else {
          if (RELU) v = fmaxf(v, 0.0f);
          if (ADDX) v += extra[(size_t)row * Nn + col];
          if (OUTBF16) ((unsigned short*)Cout)[(size_t)row * Nn + col] = f2bf(v);
          else         ((float*)Cout)[(size_t)row * Nn + col] = v;
        }
      }
    }
  }
}

// ---------- fused pair kernel (round-3 proven 205us structure + cvt_pk) ----------
// One WG = one (i,j) pair x 128 batch rows. 512 threads (8 waves), 144 KB LDS.
// Epilogue writes bf16 partial slab P[pair][512][256] with plain stores;
// k_reduce sums the 15 slabs per i afterwards.
__global__ __launch_bounds__(512, 2) void k_pair2(
    const unsigned short* __restrict__ UV,   // [8192][1024] bf16: U' | V'+ib1
    const unsigned short* __restrict__ W2t,  // [512][512] bf16 (n,k)
    const unsigned short* __restrict__ W3t,  // [256][512] bf16 (n,k)
    const float* __restrict__ b2,
    const float* __restrict__ b3,
    unsigned short* __restrict__ P){         // [240][512][256] bf16 partials
  __shared__ __align__(16) unsigned char sA1[128 * 128];    // 16 KB  [128 m][64 k]
  __shared__ __align__(16) unsigned char sA2[128 * 1024];   // 128 KB [128 m][512 k]

  const int bid = blockIdx.x;
  const int wg  = (bid & 7) * 120 + (bid >> 3);   // bijective XCD swizzle
  const int p   = wg >> 2;               // pair 0..239
  const int q4  = wg & 3;                // 128-row quarter
  const int i   = p / 15;
  const int rj  = p - i * 15;
  const int j   = rj + (rj >= i ? 1 : 0);
  const int b0  = q4 * 128;

  const int t = threadIdx.x;
  const int w = t >> 6, l = t & 63, l15 = l & 15, lq = l >> 4;
  const int n0w = w * 64;

  const unsigned short* Up = UV + (((size_t)(i * BB + b0)) << 10);
  const unsigned short* Vp = UV + (((size_t)(j * BB + b0)) << 10) + 512;

  const int sr = t >> 2, sk = (t & 3) << 4;
  const size_t srow = (size_t)sr << 10;
  const unsigned sbase = (unsigned)((sr << 7) + (sk << 1));
  const unsigned ssw = (unsigned)((sr & 7) << 4);

  v8s u0, u1, v0, v1;
  u0 = *(const v8s*)(Up + srow + sk);
  u1 = *(const v8s*)(Up + srow + sk + 8);
  v0 = *(const v8s*)(Vp + srow + sk);
  v1 = *(const v8s*)(Vp + srow + sk + 8);

  v4f c2[4][8];
#pragma unroll
  for (int nf = 0; nf < 4; nf++)
#pragma unroll
    for (int mf = 0; mf < 8; mf++) c2[nf][mf] = (v4f){0.f, 0.f, 0.f, 0.f};

  for (int kt = 0; kt < 512; kt += 64){
    if (kt) __syncthreads();
    { // convert staged regs -> sA1 via packed cvt (f0/f1 fully unrolled -> regs)
      float f0[8], f1[8];
#pragma unroll
      for (int e = 0; e < 8; e++){
        f0[e] = fmaxf(bf2f((unsigned short)u0[e]) + bf2f((unsigned short)v0[e]), 0.f);
        f1[e] = fmaxf(bf2f((unsigned short)u1[e]) + bf2f((unsigned short)v1[e]), 0.f);
      }
      uint4 q0, q1;
      q0.x = cvt_pk(f0[0], f0[1]); q0.y = cvt_pk(f0[2], f0[3]);
      q0.z = cvt_pk(f0[4], f0[5]); q0.w = cvt_pk(f0[6], f0[7]);
      q1.x = cvt_pk(f1[0], f1[1]); q1.y = cvt_pk(f1[2], f1[3]);
      q1.z = cvt_pk(f1[4], f1[5]); q1.w = cvt_pk(f1[6], f1[7]);
      *(uint4*)(sA1 + (sbase ^ ssw)) = q0;
      *(uint4*)(sA1 + ((sbase + 16) ^ ssw)) = q1;
    }
    __syncthreads();
    if (kt < 448){                       // prefetch next tile
      u0 = *(const v8s*)(Up + srow + kt + 64 + sk);
      u1 = *(const v8s*)(Up + srow + kt + 64 + sk + 8);
      v0 = *(const v8s*)(Vp + srow + kt + 64 + sk);
      v1 = *(const v8s*)(Vp + srow + kt + 64 + sk + 8);
    }
#pragma unroll
    for (int kb = 0; kb < 64; kb += 32){
      v8s a1f[8], w2f[4];
#pragma unroll
      for (int nf = 0; nf < 4; nf++)
        w2f[nf] = *(const v8s*)(W2t + (((size_t)(n0w + nf * 16 + l15)) << 9) + kt + kb + (lq << 3));
#pragma unroll
      for (int mf = 0; mf < 8; mf++){
        const int row = mf * 16 + l15;
        a1f[mf] = *(const v8s*)(sA1 + ((unsigned)((row << 7) + ((kb + (lq << 3)) << 1)) ^ (unsigned)((row & 7) << 4)));
      }
      __builtin_amdgcn_s_setprio(1);
#pragma unroll
      for (int nf = 0; nf < 4; nf++)
#pragma unroll
        for (int mf = 0; mf < 8; mf++)
          c2[nf][mf] = MFMA16(w2f[nf], a1f[mf], c2[nf][mf]);
      __builtin_amdgcn_s_setprio(0);
    }
  }

  // A2 = relu(c2 + b2) -> sA2 [m][k] packed b64 via cvt_pk
#pragma unroll
  for (int nf = 0; nf < 4; nf++){
    const float4 bb = *(const float4*)(b2 + n0w + nf * 16 + (lq << 2));
#pragma unroll
    for (int mf = 0; mf < 8; mf++){
      v4f vv = c2[nf][mf];
      unsigned lo = cvt_pk(fmaxf(vv[0] + bb.x, 0.f), fmaxf(vv[1] + bb.y, 0.f));
      unsigned hi = cvt_pk(fmaxf(vv[2] + bb.z, 0.f), fmaxf(vv[3] + bb.w, 0.f));
      const int row = mf * 16 + l15;
      const unsigned addr = (unsigned)((row << 10) + ((n0w + nf * 16 + (lq << 2)) << 1)) ^ (unsigned)((row & 7) << 4);
      *(uint2*)(sA2 + addr) = make_uint2(lo, hi);
    }
  }
  __syncthreads();

  // GEMM3: barrier-free. wave grid 2m x 4n
  const int wm = w & 1, wn = w >> 1;
  v4f c3[4][4];
#pragma unroll
  for (int mf = 0; mf < 4; mf++)
#pragma unroll
    for (int nf = 0; nf < 4; nf++) c3[mf][nf] = (v4f){0.f, 0.f, 0.f, 0.f};

#pragma unroll 2
  for (int kb3 = 0; kb3 < 512; kb3 += 32){
    v8s a2f[4], w3f[4];
#pragma unroll
    for (int nf = 0; nf < 4; nf++)
      w3f[nf] = *(const v8s*)(W3t + (((size_t)(wn * 64 + nf * 16 + l15)) << 9) + kb3 + (lq << 3));
#pragma unroll
    for (int mf = 0; mf < 4; mf++){
      const int row = wm * 64 + mf * 16 + l15;
      a2f[mf] = *(const v8s*)(sA2 + ((unsigned)((row << 10) + ((kb3 + (lq << 3)) << 1)) ^ (unsigned)((row & 7) << 4)));
    }
    __builtin_amdgcn_s_setprio(1);
#pragma unroll
    for (int mf = 0; mf < 4; mf++)
#pragma unroll
      for (int nf = 0; nf < 4; nf++)
        c3[mf][nf] = MFMA16(a2f[mf], w3f[nf], c3[mf][nf]);
    __builtin_amdgcn_s_setprio(0);
  }

  // epilogue: plain bf16 stores into pair slab
  unsigned short* pb = P + ((size_t)p << 17) + (((size_t)(b0 + wm * 64)) << 8);
#pragma unroll
  for (int nf = 0; nf < 4; nf++){
    const int col = wn * 64 + nf * 16 + l15;
    const float b3v = b3[col];
#pragma unroll
    for (int mf = 0; mf < 4; mf++){
#pragma unroll
      for (int e = 0; e < 4; e++){
        const int row = mf * 16 + (lq << 2) + e;
        pb[((size_t)row << 8) + col] = f2bf(fmaxf(c3[mf][nf][e] + b3v, 0.f));
      }
    }
  }
}

// ---------- slab reduction: out += sum_{15 slabs of i} P (16B/lane) ----------
__global__ __launch_bounds__(256) void k_reduce(const unsigned short* __restrict__ P,
                                                float* __restrict__ out){
  int idx = blockIdx.x * 256 + threadIdx.x;     // one thread per 8 cols; 262144 total
  const int c8  = (idx & 31) << 3;
  const int row = idx >> 5;                     // 0..8191
  const int i   = row >> 9;
  const unsigned short* pb = P + (((size_t)(i * 15)) << 17) + (((size_t)(row & 511)) << 8) + c8;
  float s[8] = {0.f,0.f,0.f,0.f,0.f,0.f,0.f,0.f};
#pragma unroll
  for (int sl = 0; sl < 15; sl++){
    v8s v = *(const v8s*)(pb + ((size_t)sl << 17));
#pragma unroll
    for (int e = 0; e < 8; e++) s[e] += bf2f((unsigned short)v[e]);
  }
  float* op = out + ((size_t)row << 8) + c8;
  float4 o0 = *(float4*)(op), o1 = *(float4*)(op + 4);
  o0.x += s[0]; o0.y += s[1]; o0.z += s[2]; o0.w += s[3];
  o1.x += s[4]; o1.y += s[5]; o1.z += s[6]; o1.w += s[7];
  *(float4*)(op) = o0; *(float4*)(op + 4) = o1;
}

// ---------- host ----------

extern "C" void kernel_launch(void* const* d_in, const int* in_sizes, int n_in,
                              void* d_out, int out_size, void* d_ws, size_t ws_size,
                              hipStream_t stream){
  const float* objs = (const float*)d_in[0];
  const float* tW1  = (const float*)d_in[1];
  const float* tb1  = (const float*)d_in[2];
  const float* tW2  = (const float*)d_in[3];
  const float* tb2  = (const float*)d_in[4];
  const float* tW3  = (const float*)d_in[5];
  const float* tb3  = (const float*)d_in[6];
  const float* iW1  = (const float*)d_in[7];
  const float* ib1  = (const float*)d_in[8];
  const float* iW2  = (const float*)d_in[9];
  const float* ib2  = (const float*)d_in[10];
  const float* iW3  = (const float*)d_in[11];
  const float* ib3  = (const float*)d_in[12];

  char* ws = (char*)d_ws;
  size_t off = 0;
  unsigned short* objsb = (unsigned short*)(ws + off); off += (size_t)RR * DD * 2;        // 4 MB
  unsigned short* H1    = (unsigned short*)(ws + off); off += (size_t)RR * 512 * 2;       // 8 MB
  unsigned short* H2    = (unsigned short*)(ws + off); off += (size_t)RR * 512 * 2;       // 8 MB
  unsigned short* UVb   = (unsigned short*)(ws + off); off += (size_t)RR * 1024 * 2;      // 16 MB
  unsigned short* Wcat  = (unsigned short*)(ws + off); off += 1536 * 256 * 2;
  unsigned short* tW2t  = (unsigned short*)(ws + off); off += 512 * 512 * 2;
  unsigned short* tW3t  = (unsigned short*)(ws + off); off += 256 * 512 * 2;
  unsigned short* iW2t  = (unsigned short*)(ws + off); off += 512 * 512 * 2;
  unsigned short* iW3t  = (unsigned short*)(ws + off); off += 256 * 512 * 2;
  float*          bcat  = (float*)(ws + off);          off += 1536 * 4;
  unsigned short* P     = (unsigned short*)(ws + off); off += (size_t)240 * 512 * 256 * 2; // 60 MB
  (void)ws_size; (void)in_sizes; (void)n_in; (void)out_size;

  // prep
  k_cast4<<<dim3((RR * DD / 4 + 255) / 256), dim3(256), 0, stream>>>(objs, objsb, RR * DD / 4);
  k_prep<<<dim3(4614), dim3(256), 0, stream>>>(tW1, tW2, tW3, iW1, iW2, iW3, tb1, ib1,
                                               Wcat, tW2t, tW3t, iW2t, iW3t, bcat);

  // merged H1 + UV GEMM (split epilogue): H1 = relu(objs@tW1+tb1), UV = objs@iW1ab + [0|ib1]
  k_gemm<256, true, false, false, true ><<<dim3(RR / 64, 12), dim3(256), 0, stream>>>(
      objsb, Wcat, bcat, H1, nullptr, UVb, RR, 1536);
  // H2 = relu(H1@tW2+tb2)
  k_gemm<512, true, true,  false, false><<<dim3(RR / 64, 4), dim3(256), 0, stream>>>(
      H1, tW2t, tb2, H2, nullptr, nullptr, RR, 512);
  // T path: out = relu(H2@tW3+tb3) + objs
  k_gemm<512, false, true, true,  false><<<dim3(RR / 64, 2), dim3(256), 0, stream>>>(
      H2, tW3t, tb3, d_out, objs, nullptr, RR, DD);

  // fused pair interaction -> bf16 partial slabs (no atomics)
  k_pair2<<<dim3(960), dim3(512), 0, stream>>>(UVb, iW2t, iW3t, ib2, ib3, P);

  // out += sum of 15 slabs per i
  k_reduce<<<dim3(1024), dim3(256), 0, stream>>>(P, (float*)d_out);
}

// Round 8
// 209.028 us; speedup vs baseline: 2.3176x; 1.2669x over previous
//
#include <hip/hip_runtime.h>

#define NN 16
#define BB 512
#define DD 256
#define RR (NN*BB)   // 8192

typedef __attribute__((ext_vector_type(8))) short v8s;
typedef __attribute__((ext_vector_type(4))) float v4f;
typedef __attribute__((ext_vector_type(4))) unsigned v4u;

#define MFMA16(a,b,c) __builtin_amdgcn_mfma_f32_16x16x32_bf16((a),(b),(c),0,0,0)

__device__ __forceinline__ unsigned short f2bf(float f){
  unsigned int x = __float_as_uint(f);
  x += 0x7fffu + ((x >> 16) & 1u);
  return (unsigned short)(x >> 16);
}
__device__ __forceinline__ float bf2f(unsigned short u){
  return __uint_as_float(((unsigned int)u) << 16);
}
// packed f32x2 -> bf16x2 (S0 -> low16, S1 -> high16), RTNE — same as f2bf
__device__ __forceinline__ unsigned cvt_pk(float lo, float hi){
  unsigned r;
  asm("v_cvt_pk_bf16_f32 %0, %1, %2" : "=v"(r) : "v"(lo), "v"(hi));
  return r;
}

// ---------- prep kernels ----------

__global__ __launch_bounds__(256) void k_cast4(const float* __restrict__ in,
                                               unsigned short* __restrict__ out, int n4){
  int idx = blockIdx.x * 256 + threadIdx.x;
  if (idx < n4){
    float4 v = ((const float4*)in)[idx];
    ushort4 o;
    o.x = f2bf(v.x); o.y = f2bf(v.y); o.z = f2bf(v.z); o.w = f2bf(v.w);
    ((ushort4*)out)[idx] = o;
  }
}

// weight transposes + concat + bias concat in one launch.
// Wcat [1536][256]: rows 0..511 = tW1^T ; 512..1023 = iW1-top^T ; 1024..1535 = iW1-bot^T
// bcat [1536] = [tb1 | 0 | ib1]
// iW2q/iW3q: fragment-order layout for k_pair2:
//   element (n,k) -> [(k>>5)*NB + (n>>4)][(k>>3)&3][n&15][k&7]  (NB = N/16)
//   so one wave B-frag load (lanes l = lq*16+l15, 16B each) is 1KB contiguous.
__global__ __launch_bounds__(256) void k_prep(
    const float* __restrict__ tW1, const float* __restrict__ tW2, const float* __restrict__ tW3,
    const float* __restrict__ iW1, const float* __restrict__ iW2, const float* __restrict__ iW3,
    const float* __restrict__ tb1, const float* __restrict__ ib1,
    unsigned short* __restrict__ Wcat, unsigned short* __restrict__ tW2t, unsigned short* __restrict__ tW3t,
    unsigned short* __restrict__ iW2q, unsigned short* __restrict__ iW3q,
    float* __restrict__ bcat){
  int idx = blockIdx.x * 256 + threadIdx.x;
  if (idx < 131072){                                   // Wcat rows 0..511 <- tW1 [256][512]
    int n = idx >> 8, k = idx & 255;
    Wcat[idx] = f2bf(tW1[k * 512 + n]);
    return;
  }
  idx -= 131072;
  if (idx < 262144){                                   // tW2t [512][512]
    int n = idx >> 9, k = idx & 511;
    tW2t[idx] = f2bf(tW2[k * 512 + n]);
    return;
  }
  idx -= 262144;
  if (idx < 131072){                                   // tW3t [256][512] <- tW3 [512][256]
    int n = idx >> 9, k = idx & 511;
    tW3t[idx] = f2bf(tW3[k * 256 + n]);
    return;
  }
  idx -= 131072;
  if (idx < 262144){                                   // iW2q (frag-order) <- iW2 [512][512]
    int n = idx >> 9, k = idx & 511;
    int d = (((k >> 5) * 32 + (n >> 4)) << 9) + (((k >> 3) & 3) << 7) + ((n & 15) << 3) + (k & 7);
    iW2q[d] = f2bf(iW2[k * 512 + n]);
    return;
  }
  idx -= 262144;
  if (idx < 131072){                                   // iW3q (frag-order) <- iW3 [512][256]
    int n = idx >> 9, k = idx & 511;
    int d = (((k >> 5) * 16 + (n >> 4)) << 9) + (((k >> 3) & 3) << 7) + ((n & 15) << 3) + (k & 7);
    iW3q[d] = f2bf(iW3[k * 256 + n]);
    return;
  }
  idx -= 131072;
  if (idx < 262144){                                   // Wcat rows 512..1535 <- iW1 split
    int r = idx >> 8, k = idx & 255;
    float v = (r < 512) ? iW1[k * 512 + r] : iW1[(k + 256) * 512 + (r - 512)];
    Wcat[(512 << 8) + idx] = f2bf(v);
    return;
  }
  idx -= 262144;
  if (idx < 1536)
    bcat[idx] = (idx < 512) ? tb1[idx] : ((idx < 1024) ? 0.f : ib1[idx - 1024]);
}

// ---------- phase-A GEMM ----------
// C[M][Nn] = act(A[M][KD] @ Wt[Nn][KD]^T + bias) (+ extra); SPLIT: H1(relu)/UV(bias)
template<int KD, bool OUTBF16, bool RELU, bool ADDX, bool SPLIT>
__global__ __launch_bounds__(256) void k_gemm(const unsigned short* __restrict__ A,
                                              const unsigned short* __restrict__ Wt,
                                              const float* __restrict__ bias,
                                              void* __restrict__ Cout,
                                              const float* __restrict__ extra,
                                              void* __restrict__ Cout2,
                                              int M, int Nn){
  __shared__ __align__(16) unsigned char sA[64 * 128];
  __shared__ __align__(16) unsigned char sB[128 * 128];
  const int m0 = blockIdx.x * 64;
  const int n0 = blockIdx.y * 128;
  const int t = threadIdx.x;
  const int w = t >> 6, l = t & 63;
  const int l15 = l & 15, lq = l >> 4;
  const int rowh = (w & 1) * 32, colh = (w >> 1) * 64;

  v4f c[2][4];
#pragma unroll
  for (int r = 0; r < 2; r++)
#pragma unroll
    for (int q = 0; q < 4; q++) c[r][q] = (v4f){0.f, 0.f, 0.f, 0.f};

  for (int kt = 0; kt < KD; kt += 64){
    __syncthreads();
    {
      const int row = t >> 2, cq = (t & 3) * 16;
      const unsigned short* src = A + (size_t)(m0 + row) * KD + kt + cq;
      v8s a0 = *(const v8s*)(src);
      v8s a1 = *(const v8s*)(src + 8);
      const unsigned sw = (unsigned)((row & 7) << 4);
      *(v8s*)(sA + ((unsigned)((row << 7) + (cq << 1)) ^ sw)) = a0;
      *(v8s*)(sA + ((unsigned)((row << 7) + (cq << 1) + 16) ^ sw)) = a1;
    }
    {
      const int n = t & 127, kq = (t >> 7) * 32;
      const unsigned short* src = Wt + (size_t)(n0 + n) * KD + kt + kq;
      const unsigned base = (unsigned)((n << 7) + (kq << 1));
      const unsigned sw = (unsigned)((n & 7) << 4);
#pragma unroll
      for (int q = 0; q < 4; q++){
        v8s v = *(const v8s*)(src + q * 8);
        *(v8s*)(sB + ((base + q * 16) ^ sw)) = v;
      }
    }
    __syncthreads();
#pragma unroll
    for (int kb = 0; kb < 64; kb += 32){
      v8s af[2], bfr[4];
#pragma unroll
      for (int r = 0; r < 2; r++){
        const int row = rowh + r * 16 + l15;
        af[r] = *(const v8s*)(sA + ((unsigned)((row << 7) + ((kb + (lq << 3)) << 1)) ^ (unsigned)((row & 7) << 4)));
      }
#pragma unroll
      for (int q = 0; q < 4; q++){
        const int n = colh + q * 16 + l15;
        bfr[q] = *(const v8s*)(sB + ((unsigned)((n << 7) + ((kb + (lq << 3)) << 1)) ^ (unsigned)((n & 7) << 4)));
      }
#pragma unroll
      for (int r = 0; r < 2; r++)
#pragma unroll
        for (int q = 0; q < 4; q++)
          c[r][q] = MFMA16(af[r], bfr[q], c[r][q]);
    }
  }
#pragma unroll
  for (int r = 0; r < 2; r++){
#pragma unroll
    for (int q = 0; q < 4; q++){
      const int col = n0 + colh + q * 16 + l15;
      const float bv = bias ? bias[col] : 0.0f;
#pragma unroll
      for (int e = 0; e < 4; e++){
        const int row = m0 + rowh + r * 16 + (lq << 2) + e;
        float v = c[r][q][e] + bv;
        if (SPLIT){
          if (col < 512){
            ((unsigned short*)Cout)[(size_t)row * 512 + col] = f2bf(fmaxf(v, 0.0f));
          } else {
            ((unsigned short*)Cout2)[(size_t)row * 1024 + (col - 512)] = f2bf(v);
          }
        } else {
          if (RELU) v = fmaxf(v, 0.0f);
          if (ADDX) v += extra[(size_t)row * Nn + col];
          if (OUTBF16) ((unsigned short*)Cout)[(size_t)row * Nn + col] = f2bf(v);
          else         ((float*)Cout)[(size_t)row * Nn + col] = v;
        }
      }
    }
  }
}

// ---------- fused pair kernel ----------
// One WG = one (i,j) pair x 128 batch rows. 512 threads (8 waves), 144 KB LDS.
// W2/W3 in fragment-order layout (1KB-contiguous wave loads). Epilogue writes
// a PERMUTED bf16 partial slab P[pair] (store-optimal order) with NON-TEMPORAL
// packed stores; k_reduce decodes + sums the 15 slabs per i.
// P'' within-slab ushort index:
//   ((seg*16 + wn*4 + mf)*2 + half)*512 + l*8 + (nf&1)*4 + e
//   seg = q4*2+wm (64-row segment), half = nf>>1, l = lq*16+l15.
//   logical (row,col) = (seg*64+mf*16+lq*4+e, wn*64+nf*16+l15)
__global__ __launch_bounds__(512, 2) void k_pair2(
    const unsigned short* __restrict__ UV,   // [8192][1024] bf16: U' | V'+ib1
    const unsigned short* __restrict__ W2q,  // frag-order [16][32][512]
    const unsigned short* __restrict__ W3q,  // frag-order [16][16][512]
    const float* __restrict__ b2,
    const float* __restrict__ b3,
    unsigned short* __restrict__ P){         // [240][131072] bf16 partials (permuted)
  __shared__ __align__(16) unsigned char sA1[128 * 128];    // 16 KB  [128 m][64 k]
  __shared__ __align__(16) unsigned char sA2[128 * 1024];   // 128 KB [128 m][512 k]

  const int bid = blockIdx.x;
  const int wg  = (bid & 7) * 120 + (bid >> 3);   // bijective XCD swizzle
  const int p   = wg >> 2;               // pair 0..239
  const int q4  = wg & 3;                // 128-row quarter
  const int i   = p / 15;
  const int rj  = p - i * 15;
  const int j   = rj + (rj >= i ? 1 : 0);
  const int b0  = q4 * 128;

  const int t = threadIdx.x;
  const int w = t >> 6, l = t & 63, l15 = l & 15, lq = l >> 4;
  const int n0w = w * 64;

  const unsigned short* Up = UV + (((size_t)(i * BB + b0)) << 10);
  const unsigned short* Vp = UV + (((size_t)(j * BB + b0)) << 10) + 512;

  const int sr = t >> 2, sk = (t & 3) << 4;
  const size_t srow = (size_t)sr << 10;
  const unsigned sbase = (unsigned)((sr << 7) + (sk << 1));
  const unsigned ssw = (unsigned)((sr & 7) << 4);

  // fragment-order weight bases: per-lane constant offset, contiguous per instr
  const unsigned short* W2l = W2q + ((size_t)(w * 4) << 9) + (lq << 7) + (l15 << 3);
  const unsigned short* W3l = W3q + (lq << 7) + (l15 << 3);   // wn-dependent base added later

  v8s u0, u1, v0, v1;
  u0 = *(const v8s*)(Up + srow + sk);
  u1 = *(const v8s*)(Up + srow + sk + 8);
  v0 = *(const v8s*)(Vp + srow + sk);
  v1 = *(const v8s*)(Vp + srow + sk + 8);

  v4f c2[4][8];
#pragma unroll
  for (int nf = 0; nf < 4; nf++)
#pragma unroll
    for (int mf = 0; mf < 8; mf++) c2[nf][mf] = (v4f){0.f, 0.f, 0.f, 0.f};

  for (int kt = 0; kt < 512; kt += 64){
    if (kt) __syncthreads();
    { // convert staged regs -> sA1 via packed cvt
      float f0[8], f1[8];
#pragma unroll
      for (int e = 0; e < 8; e++){
        f0[e] = fmaxf(bf2f((unsigned short)u0[e]) + bf2f((unsigned short)v0[e]), 0.f);
        f1[e] = fmaxf(bf2f((unsigned short)u1[e]) + bf2f((unsigned short)v1[e]), 0.f);
      }
      v4u q0, q1;
      q0.x = cvt_pk(f0[0], f0[1]); q0.y = cvt_pk(f0[2], f0[3]);
      q0.z = cvt_pk(f0[4], f0[5]); q0.w = cvt_pk(f0[6], f0[7]);
      q1.x = cvt_pk(f1[0], f1[1]); q1.y = cvt_pk(f1[2], f1[3]);
      q1.z = cvt_pk(f1[4], f1[5]); q1.w = cvt_pk(f1[6], f1[7]);
      *(v4u*)(sA1 + (sbase ^ ssw)) = q0;
      *(v4u*)(sA1 + ((sbase + 16) ^ ssw)) = q1;
    }
    __syncthreads();
    if (kt < 448){                       // prefetch next tile
      u0 = *(const v8s*)(Up + srow + kt + 64 + sk);
      u1 = *(const v8s*)(Up + srow + kt + 64 + sk + 8);
      v0 = *(const v8s*)(Vp + srow + kt + 64 + sk);
      v1 = *(const v8s*)(Vp + srow + kt + 64 + sk + 8);
    }
#pragma unroll
    for (int kb = 0; kb < 64; kb += 32){
      v8s a1f[8], w2f[4];
      const unsigned short* W2s = W2l + ((size_t)((kt + kb) >> 5) << 14);
#pragma unroll
      for (int nf = 0; nf < 4; nf++)
        w2f[nf] = *(const v8s*)(W2s + (nf << 9));
#pragma unroll
      for (int mf = 0; mf < 8; mf++){
        const int row = mf * 16 + l15;
        a1f[mf] = *(const v8s*)(sA1 + ((unsigned)((row << 7) + ((kb + (lq << 3)) << 1)) ^ (unsigned)((row & 7) << 4)));
      }
      __builtin_amdgcn_s_setprio(1);
#pragma unroll
      for (int nf = 0; nf < 4; nf++)
#pragma unroll
        for (int mf = 0; mf < 8; mf++)
          c2[nf][mf] = MFMA16(w2f[nf], a1f[mf], c2[nf][mf]);
      __builtin_amdgcn_s_setprio(0);
    }
  }

  // A2 = relu(c2 + b2) -> sA2 [m][k] packed b64 via cvt_pk
#pragma unroll
  for (int nf = 0; nf < 4; nf++){
    const float4 bb = *(const float4*)(b2 + n0w + nf * 16 + (lq << 2));
#pragma unroll
    for (int mf = 0; mf < 8; mf++){
      v4f vv = c2[nf][mf];
      unsigned lo = cvt_pk(fmaxf(vv[0] + bb.x, 0.f), fmaxf(vv[1] + bb.y, 0.f));
      unsigned hi = cvt_pk(fmaxf(vv[2] + bb.z, 0.f), fmaxf(vv[3] + bb.w, 0.f));
      const int row = mf * 16 + l15;
      const unsigned addr = (unsigned)((row << 10) + ((n0w + nf * 16 + (lq << 2)) << 1)) ^ (unsigned)((row & 7) << 4);
      *(uint2*)(sA2 + addr) = make_uint2(lo, hi);
    }
  }
  __syncthreads();

  // GEMM3: barrier-free. wave grid 2m x 4n
  const int wm = w & 1, wn = w >> 1;
  const unsigned short* W3b = W3l + ((size_t)(wn * 4) << 9);
  v4f c3[4][4];
#pragma unroll
  for (int mf = 0; mf < 4; mf++)
#pragma unroll
    for (int nf = 0; nf < 4; nf++) c3[mf][nf] = (v4f){0.f, 0.f, 0.f, 0.f};

#pragma unroll 2
  for (int kb3 = 0; kb3 < 512; kb3 += 32){
    v8s a2f[4], w3f[4];
    const unsigned short* W3s = W3b + ((size_t)(kb3 >> 5) << 13);
#pragma unroll
    for (int nf = 0; nf < 4; nf++)
      w3f[nf] = *(const v8s*)(W3s + (nf << 9));
#pragma unroll
    for (int mf = 0; mf < 4; mf++){
      const int row = wm * 64 + mf * 16 + l15;
      a2f[mf] = *(const v8s*)(sA2 + ((unsigned)((row << 10) + ((kb3 + (lq << 3)) << 1)) ^ (unsigned)((row & 7) << 4)));
    }
    __builtin_amdgcn_s_setprio(1);
#pragma unroll
    for (int mf = 0; mf < 4; mf++)
#pragma unroll
      for (int nf = 0; nf < 4; nf++)
        c3[mf][nf] = MFMA16(a2f[mf], w3f[nf], c3[mf][nf]);
    __builtin_amdgcn_s_setprio(0);
  }

  // epilogue: packed NON-TEMPORAL stores into permuted pair slab (2x16B per mf)
  {
    const float b3v0 = b3[wn * 64 +  0 + l15];
    const float b3v1 = b3[wn * 64 + 16 + l15];
    const float b3v2 = b3[wn * 64 + 32 + l15];
    const float b3v3 = b3[wn * 64 + 48 + l15];
    const int seg = q4 * 2 + wm;
    unsigned short* pb = P + ((size_t)p << 17) + ((size_t)l << 3);
#pragma unroll
    for (int mf = 0; mf < 4; mf++){
      v4u h0, h1;
      h0.x = cvt_pk(fmaxf(c3[mf][0][0] + b3v0, 0.f), fmaxf(c3[mf][0][1] + b3v0, 0.f));
      h0.y = cvt_pk(fmaxf(c3[mf][0][2] + b3v0, 0.f), fmaxf(c3[mf][0][3] + b3v0, 0.f));
      h0.z = cvt_pk(fmaxf(c3[mf][1][0] + b3v1, 0.f), fmaxf(c3[mf][1][1] + b3v1, 0.f));
      h0.w = cvt_pk(fmaxf(c3[mf][1][2] + b3v1, 0.f), fmaxf(c3[mf][1][3] + b3v1, 0.f));
      h1.x = cvt_pk(fmaxf(c3[mf][2][0] + b3v2, 0.f), fmaxf(c3[mf][2][1] + b3v2, 0.f));
      h1.y = cvt_pk(fmaxf(c3[mf][2][2] + b3v2, 0.f), fmaxf(c3[mf][2][3] + b3v2, 0.f));
      h1.z = cvt_pk(fmaxf(c3[mf][3][0] + b3v3, 0.f), fmaxf(c3[mf][3][1] + b3v3, 0.f));
      h1.w = cvt_pk(fmaxf(c3[mf][3][2] + b3v3, 0.f), fmaxf(c3[mf][3][3] + b3v3, 0.f));
      const int B = ((seg * 16 + wn * 4 + mf) << 1);
      __builtin_nontemporal_store(h0, (v4u*)(pb + ((size_t)B << 9)));
      __builtin_nontemporal_store(h1, (v4u*)(pb + ((size_t)(B + 1) << 9)));
    }
  }
}

// ---------- slab reduction: out += sum_{15 slabs of i} P (decode permuted) ----------
__global__ __launch_bounds__(256) void k_reduce(const unsigned short* __restrict__ P,
                                                float* __restrict__ out){
  int idx = blockIdx.x * 256 + threadIdx.x;     // 262144 threads, 8 elems each
  const int i = idx >> 14;
  const int g = idx & 16383;                    // = B*64 + l
  const unsigned short* pb = P + (((size_t)(i * 15)) << 17) + ((size_t)g << 3);
  float s[8] = {0.f,0.f,0.f,0.f,0.f,0.f,0.f,0.f};
#pragma unroll
  for (int sl = 0; sl < 15; sl++){
    v8s v = __builtin_nontemporal_load((const v8s*)(pb + ((size_t)sl << 17)));
#pragma unroll
    for (int e = 0; e < 8; e++) s[e] += bf2f((unsigned short)v[e]);
  }
  // decode: B -> (seg, wn, mf, half); l -> (lq, l15); elem j -> (nf&1 = j>>2, e = j&3)
  const int l = g & 63, B = g >> 6;
  const int half = B & 1, mf = (B >> 1) & 3, wn = (B >> 3) & 3, seg = B >> 5;
  const int rowb = (i << 9) + seg * 64 + mf * 16 + ((l >> 4) << 2);
  const int colb = wn * 64 + half * 32 + (l & 15);
  float* ob = out + ((size_t)rowb << 8) + colb;
#pragma unroll
  for (int jj = 0; jj < 2; jj++)
#pragma unroll
    for (int e = 0; e < 4; e++)
      ob[(e << 8) + jj * 16] += s[jj * 4 + e];
}

// ---------- host ----------

extern "C" void kernel_launch(void* const* d_in, const int* in_sizes, int n_in,
                              void* d_out, int out_size, void* d_ws, size_t ws_size,
                              hipStream_t stream){
  const float* objs = (const float*)d_in[0];
  const float* tW1  = (const float*)d_in[1];
  const float* tb1  = (const float*)d_in[2];
  const float* tW2  = (const float*)d_in[3];
  const float* tb2  = (const float*)d_in[4];
  const float* tW3  = (const float*)d_in[5];
  const float* tb3  = (const float*)d_in[6];
  const float* iW1  = (const float*)d_in[7];
  const float* ib1  = (const float*)d_in[8];
  const float* iW2  = (const float*)d_in[9];
  const float* ib2  = (const float*)d_in[10];
  const float* iW3  = (const float*)d_in[11];
  const float* ib3  = (const float*)d_in[12];

  char* ws = (char*)d_ws;
  size_t off = 0;
  unsigned short* objsb = (unsigned short*)(ws + off); off += (size_t)RR * DD * 2;        // 4 MB
  unsigned short* H1    = (unsigned short*)(ws + off); off += (size_t)RR * 512 * 2;       // 8 MB
  unsigned short* H2    = (unsigned short*)(ws + off); off += (size_t)RR * 512 * 2;       // 8 MB
  unsigned short* UVb   = (unsigned short*)(ws + off); off += (size_t)RR * 1024 * 2;      // 16 MB
  unsigned short* Wcat  = (unsigned short*)(ws + off); off += 1536 * 256 * 2;
  unsigned short* tW2t  = (unsigned short*)(ws + off); off += 512 * 512 * 2;
  unsigned short* tW3t  = (unsigned short*)(ws + off); off += 256 * 512 * 2;
  unsigned short* iW2q  = (unsigned short*)(ws + off); off += 512 * 512 * 2;
  unsigned short* iW3q  = (unsigned short*)(ws + off); off += 256 * 512 * 2;
  float*          bcat  = (float*)(ws + off);          off += 1536 * 4;
  unsigned short* P     = (unsigned short*)(ws + off); off += (size_t)240 * 512 * 256 * 2; // 60 MB
  (void)ws_size; (void)in_sizes; (void)n_in; (void)out_size;

  // prep
  k_cast4<<<dim3((RR * DD / 4 + 255) / 256), dim3(256), 0, stream>>>(objs, objsb, RR * DD / 4);
  k_prep<<<dim3(4614), dim3(256), 0, stream>>>(tW1, tW2, tW3, iW1, iW2, iW3, tb1, ib1,
                                               Wcat, tW2t, tW3t, iW2q, iW3q, bcat);

  // merged H1 + UV GEMM (split epilogue): H1 = relu(objs@tW1+tb1), UV = objs@iW1ab + [0|ib1]
  k_gemm<256, true, false, false, true ><<<dim3(RR / 64, 12), dim3(256), 0, stream>>>(
      objsb, Wcat, bcat, H1, nullptr, UVb, RR, 1536);
  // H2 = relu(H1@tW2+tb2)
  k_gemm<512, true, true,  false, false><<<dim3(RR / 64, 4), dim3(256), 0, stream>>>(
      H1, tW2t, tb2, H2, nullptr, nullptr, RR, 512);
  // T path: out = relu(H2@tW3+tb3) + objs
  k_gemm<512, false, true, true,  false><<<dim3(RR / 64, 2), dim3(256), 0, stream>>>(
      H2, tW3t, tb3, d_out, objs, nullptr, RR, DD);

  // fused pair interaction -> bf16 permuted partial slabs (nt stores)
  k_pair2<<<dim3(960), dim3(512), 0, stream>>>(UVb, iW2q, iW3q, ib2, ib3, P);

  // out += sum of 15 slabs per i
  k_reduce<<<dim3(1024), dim3(256), 0, stream>>>(P, (float*)d_out);
}

// Round 9
// 183.698 us; speedup vs baseline: 2.6371x; 1.1379x over previous
//
#include <hip/hip_runtime.h>

#define NN 16
#define BB 512
#define DD 256
#define RR (NN*BB)   // 8192

typedef __attribute__((ext_vector_type(8))) short v8s;
typedef __attribute__((ext_vector_type(4))) float v4f;
typedef __attribute__((ext_vector_type(4))) unsigned v4u;

#define MFMA16(a,b,c) __builtin_amdgcn_mfma_f32_16x16x32_bf16((a),(b),(c),0,0,0)

__device__ __forceinline__ unsigned short f2bf(float f){
  unsigned int x = __float_as_uint(f);
  x += 0x7fffu + ((x >> 16) & 1u);
  return (unsigned short)(x >> 16);
}
__device__ __forceinline__ float bf2f(unsigned short u){
  return __uint_as_float(((unsigned int)u) << 16);
}
// packed f32x2 -> bf16x2 (S0 -> low16, S1 -> high16), RTNE — same as f2bf
__device__ __forceinline__ unsigned cvt_pk(float lo, float hi){
  unsigned r;
  asm("v_cvt_pk_bf16_f32 %0, %1, %2" : "=v"(r) : "v"(lo), "v"(hi));
  return r;
}

// ---------- prep kernels ----------

__global__ __launch_bounds__(256) void k_cast4(const float* __restrict__ in,
                                               unsigned short* __restrict__ out, int n4){
  int idx = blockIdx.x * 256 + threadIdx.x;
  if (idx < n4){
    float4 v = ((const float4*)in)[idx];
    ushort4 o;
    o.x = f2bf(v.x); o.y = f2bf(v.y); o.z = f2bf(v.z); o.w = f2bf(v.w);
    ((ushort4*)out)[idx] = o;
  }
}

// weight transposes + concat + bias concat in one launch.
// Wcat [1536][256]: rows 0..511 = tW1^T ; 512..1023 = iW1-top^T ; 1024..1535 = iW1-bot^T
// bcat [1536] = [tb1 | 0 | ib1]
// iW2q/iW3q: fragment-order layout for k_pair2:
//   element (n,k) -> [(k>>5)*NB + (n>>4)][(k>>3)&3][n&15][k&7]  (NB = N/16)
//   so one wave B-frag load (lanes l = lq*16+l15, 16B each) is 1KB contiguous.
__global__ __launch_bounds__(256) void k_prep(
    const float* __restrict__ tW1, const float* __restrict__ tW2, const float* __restrict__ tW3,
    const float* __restrict__ iW1, const float* __restrict__ iW2, const float* __restrict__ iW3,
    const float* __restrict__ tb1, const float* __restrict__ ib1,
    unsigned short* __restrict__ Wcat, unsigned short* __restrict__ tW2t, unsigned short* __restrict__ tW3t,
    unsigned short* __restrict__ iW2q, unsigned short* __restrict__ iW3q,
    float* __restrict__ bcat){
  int idx = blockIdx.x * 256 + threadIdx.x;
  if (idx < 131072){                                   // Wcat rows 0..511 <- tW1 [256][512]
    int n = idx >> 8, k = idx & 255;
    Wcat[idx] = f2bf(tW1[k * 512 + n]);
    return;
  }
  idx -= 131072;
  if (idx < 262144){                                   // tW2t [512][512]
    int n = idx >> 9, k = idx & 511;
    tW2t[idx] = f2bf(tW2[k * 512 + n]);
    return;
  }
  idx -= 262144;
  if (idx < 131072){                                   // tW3t [256][512] <- tW3 [512][256]
    int n = idx >> 9, k = idx & 511;
    tW3t[idx] = f2bf(tW3[k * 256 + n]);
    return;
  }
  idx -= 131072;
  if (idx < 262144){                                   // iW2q (frag-order) <- iW2 [512][512]
    int n = idx >> 9, k = idx & 511;
    int d = (((k >> 5) * 32 + (n >> 4)) << 9) + (((k >> 3) & 3) << 7) + ((n & 15) << 3) + (k & 7);
    iW2q[d] = f2bf(iW2[k * 512 + n]);
    return;
  }
  idx -= 262144;
  if (idx < 131072){                                   // iW3q (frag-order) <- iW3 [512][256]
    int n = idx >> 9, k = idx & 511;
    int d = (((k >> 5) * 16 + (n >> 4)) << 9) + (((k >> 3) & 3) << 7) + ((n & 15) << 3) + (k & 7);
    iW3q[d] = f2bf(iW3[k * 256 + n]);
    return;
  }
  idx -= 131072;
  if (idx < 262144){                                   // Wcat rows 512..1535 <- iW1 split
    int r = idx >> 8, k = idx & 255;
    float v = (r < 512) ? iW1[k * 512 + r] : iW1[(k + 256) * 512 + (r - 512)];
    Wcat[(512 << 8) + idx] = f2bf(v);
    return;
  }
  idx -= 262144;
  if (idx < 1536)
    bcat[idx] = (idx < 512) ? tb1[idx] : ((idx < 1024) ? 0.f : ib1[idx - 1024]);
}

// ---------- phase-A GEMM ----------
// C[M][Nn] = act(A[M][KD] @ Wt[Nn][KD]^T + bias) (+ extra); SPLIT: H1(relu)/UV(bias)
template<int KD, bool OUTBF16, bool RELU, bool ADDX, bool SPLIT>
__global__ __launch_bounds__(256) void k_gemm(const unsigned short* __restrict__ A,
                                              const unsigned short* __restrict__ Wt,
                                              const float* __restrict__ bias,
                                              void* __restrict__ Cout,
                                              const float* __restrict__ extra,
                                              void* __restrict__ Cout2,
                                              int M, int Nn){
  __shared__ __align__(16) unsigned char sA[64 * 128];
  __shared__ __align__(16) unsigned char sB[128 * 128];
  const int m0 = blockIdx.x * 64;
  const int n0 = blockIdx.y * 128;
  const int t = threadIdx.x;
  const int w = t >> 6, l = t & 63;
  const int l15 = l & 15, lq = l >> 4;
  const int rowh = (w & 1) * 32, colh = (w >> 1) * 64;

  v4f c[2][4];
#pragma unroll
  for (int r = 0; r < 2; r++)
#pragma unroll
    for (int q = 0; q < 4; q++) c[r][q] = (v4f){0.f, 0.f, 0.f, 0.f};

  for (int kt = 0; kt < KD; kt += 64){
    __syncthreads();
    {
      const int row = t >> 2, cq = (t & 3) * 16;
      const unsigned short* src = A + (size_t)(m0 + row) * KD + kt + cq;
      v8s a0 = *(const v8s*)(src);
      v8s a1 = *(const v8s*)(src + 8);
      const unsigned sw = (unsigned)((row & 7) << 4);
      *(v8s*)(sA + ((unsigned)((row << 7) + (cq << 1)) ^ sw)) = a0;
      *(v8s*)(sA + ((unsigned)((row << 7) + (cq << 1) + 16) ^ sw)) = a1;
    }
    {
      const int n = t & 127, kq = (t >> 7) * 32;
      const unsigned short* src = Wt + (size_t)(n0 + n) * KD + kt + kq;
      const unsigned base = (unsigned)((n << 7) + (kq << 1));
      const unsigned sw = (unsigned)((n & 7) << 4);
#pragma unroll
      for (int q = 0; q < 4; q++){
        v8s v = *(const v8s*)(src + q * 8);
        *(v8s*)(sB + ((base + q * 16) ^ sw)) = v;
      }
    }
    __syncthreads();
#pragma unroll
    for (int kb = 0; kb < 64; kb += 32){
      v8s af[2], bfr[4];
#pragma unroll
      for (int r = 0; r < 2; r++){
        const int row = rowh + r * 16 + l15;
        af[r] = *(const v8s*)(sA + ((unsigned)((row << 7) + ((kb + (lq << 3)) << 1)) ^ (unsigned)((row & 7) << 4)));
      }
#pragma unroll
      for (int q = 0; q < 4; q++){
        const int n = colh + q * 16 + l15;
        bfr[q] = *(const v8s*)(sB + ((unsigned)((n << 7) + ((kb + (lq << 3)) << 1)) ^ (unsigned)((n & 7) << 4)));
      }
#pragma unroll
      for (int r = 0; r < 2; r++)
#pragma unroll
        for (int q = 0; q < 4; q++)
          c[r][q] = MFMA16(af[r], bfr[q], c[r][q]);
    }
  }
#pragma unroll
  for (int r = 0; r < 2; r++){
#pragma unroll
    for (int q = 0; q < 4; q++){
      const int col = n0 + colh + q * 16 + l15;
      const float bv = bias ? bias[col] : 0.0f;
#pragma unroll
      for (int e = 0; e < 4; e++){
        const int row = m0 + rowh + r * 16 + (lq << 2) + e;
        float v = c[r][q][e] + bv;
        if (SPLIT){
          if (col < 512){
            ((unsigned short*)Cout)[(size_t)row * 512 + col] = f2bf(fmaxf(v, 0.0f));
          } else {
            ((unsigned short*)Cout2)[(size_t)row * 1024 + (col - 512)] = f2bf(v);
          }
        } else {
          if (RELU) v = fmaxf(v, 0.0f);
          if (ADDX) v += extra[(size_t)row * Nn + col];
          if (OUTBF16) ((unsigned short*)Cout)[(size_t)row * Nn + col] = f2bf(v);
          else         ((float*)Cout)[(size_t)row * Nn + col] = v;
        }
      }
    }
  }
}

// ---------- fused pair kernel ----------
// One WG = one (i,j) pair x 128 batch rows. 512 threads (8 waves), 160 KB LDS.
// QUARTER-OUTER XCD mapping: per-XCD chunk of 120 WGs is [quarter][30 pairs],
// so concurrent WGs on an XCD share one 128-row quarter -> V working set
// ~2 MB + U + W < 4 MB L2 -> UV reads become L2 hits.
// sA1 DOUBLE-BUFFERED: one __syncthreads per K-step (build A1(s+1) into idle
// buffer while MFMAs read buf[s&1]; waves skew, build VALU overlaps MFMA).
// W2/W3 in fragment-order layout (1KB-contiguous wave loads). Epilogue writes
// a PERMUTED bf16 partial slab P[pair] with packed non-temporal stores.
__global__ __launch_bounds__(512, 2) void k_pair2(
    const unsigned short* __restrict__ UV,   // [8192][1024] bf16: U' | V'+ib1
    const unsigned short* __restrict__ W2q,  // frag-order [16][32][512]
    const unsigned short* __restrict__ W3q,  // frag-order [16][16][512]
    const float* __restrict__ b2,
    const float* __restrict__ b3,
    unsigned short* __restrict__ P){         // [240][131072] bf16 partials (permuted)
  __shared__ __align__(16) unsigned char sA1[2][128 * 128]; // 2 x 16 KB [128 m][64 k]
  __shared__ __align__(16) unsigned char sA2[128 * 1024];   // 128 KB [128 m][512 k]

  const int bid = blockIdx.x;
  const int xcd = bid & 7;
  const int c   = bid >> 3;              // 0..119 within XCD
  const int q4  = c / 30;                // quarter OUTER
  const int pl  = c - q4 * 30;
  const int p   = xcd * 30 + pl;         // pair 0..239 (i-major per XCD)
  const int i   = p / 15;
  const int rj  = p - i * 15;
  const int j   = rj + (rj >= i ? 1 : 0);
  const int b0  = q4 * 128;

  const int t = threadIdx.x;
  const int w = t >> 6, l = t & 63, l15 = l & 15, lq = l >> 4;
  const int n0w = w * 64;

  const unsigned short* Up = UV + (((size_t)(i * BB + b0)) << 10);
  const unsigned short* Vp = UV + (((size_t)(j * BB + b0)) << 10) + 512;

  const int sr = t >> 2, sk = (t & 3) << 4;
  const size_t srow = (size_t)sr << 10;
  const unsigned sbase = (unsigned)((sr << 7) + (sk << 1));
  const unsigned ssw = (unsigned)((sr & 7) << 4);

  // fragment-order weight bases: per-lane constant offset, contiguous per instr
  const unsigned short* W2l = W2q + ((size_t)(w * 4) << 9) + (lq << 7) + (l15 << 3);
  const unsigned short* W3l = W3q + (lq << 7) + (l15 << 3);

  v8s u0, u1, v0, v1;

  auto ld_uv = [&](int kt){
    u0 = *(const v8s*)(Up + srow + kt + sk);
    u1 = *(const v8s*)(Up + srow + kt + sk + 8);
    v0 = *(const v8s*)(Vp + srow + kt + sk);
    v1 = *(const v8s*)(Vp + srow + kt + sk + 8);
  };
  auto build_a1 = [&](unsigned char* dst){
    float f0[8], f1[8];
#pragma unroll
    for (int e = 0; e < 8; e++){
      f0[e] = fmaxf(bf2f((unsigned short)u0[e]) + bf2f((unsigned short)v0[e]), 0.f);
      f1[e] = fmaxf(bf2f((unsigned short)u1[e]) + bf2f((unsigned short)v1[e]), 0.f);
    }
    v4u q0, q1;
    q0.x = cvt_pk(f0[0], f0[1]); q0.y = cvt_pk(f0[2], f0[3]);
    q0.z = cvt_pk(f0[4], f0[5]); q0.w = cvt_pk(f0[6], f0[7]);
    q1.x = cvt_pk(f1[0], f1[1]); q1.y = cvt_pk(f1[2], f1[3]);
    q1.z = cvt_pk(f1[4], f1[5]); q1.w = cvt_pk(f1[6], f1[7]);
    *(v4u*)(dst + (sbase ^ ssw)) = q0;
    *(v4u*)(dst + ((sbase + 16) ^ ssw)) = q1;
  };

  v4f c2[4][8];
#pragma unroll
  for (int nf = 0; nf < 4; nf++)
#pragma unroll
    for (int mf = 0; mf < 8; mf++) c2[nf][mf] = (v4f){0.f, 0.f, 0.f, 0.f};

  // prologue: A1(0) into buf0; prime regs for A1(1)
  ld_uv(0);
  build_a1(&sA1[0][0]);
  ld_uv(64);

#pragma unroll
  for (int s = 0; s < 8; ++s){
    __syncthreads();                       // A1(s) visible; buf[(s+1)&1] free
    if (s < 7) build_a1(&sA1[(s + 1) & 1][0]);
    if (s < 6) ld_uv((s + 2) * 64);
    const int kt = s * 64;
    const unsigned char* bufc = &sA1[s & 1][0];
#pragma unroll
    for (int kb = 0; kb < 64; kb += 32){
      v8s a1f[8], w2f[4];
      const unsigned short* W2s = W2l + ((size_t)((kt + kb) >> 5) << 14);
#pragma unroll
      for (int nf = 0; nf < 4; nf++)
        w2f[nf] = *(const v8s*)(W2s + (nf << 9));
#pragma unroll
      for (int mf = 0; mf < 8; mf++){
        const int row = mf * 16 + l15;
        a1f[mf] = *(const v8s*)(bufc + ((unsigned)((row << 7) + ((kb + (lq << 3)) << 1)) ^ (unsigned)((row & 7) << 4)));
      }
      __builtin_amdgcn_s_setprio(1);
#pragma unroll
      for (int nf = 0; nf < 4; nf++)
#pragma unroll
        for (int mf = 0; mf < 8; mf++)
          c2[nf][mf] = MFMA16(w2f[nf], a1f[mf], c2[nf][mf]);
      __builtin_amdgcn_s_setprio(0);
    }
  }

  // A2 = relu(c2 + b2) -> sA2 [m][k] packed b64 via cvt_pk
#pragma unroll
  for (int nf = 0; nf < 4; nf++){
    const float4 bb = *(const float4*)(b2 + n0w + nf * 16 + (lq << 2));
#pragma unroll
    for (int mf = 0; mf < 8; mf++){
      v4f vv = c2[nf][mf];
      unsigned lo = cvt_pk(fmaxf(vv[0] + bb.x, 0.f), fmaxf(vv[1] + bb.y, 0.f));
      unsigned hi = cvt_pk(fmaxf(vv[2] + bb.z, 0.f), fmaxf(vv[3] + bb.w, 0.f));
      const int row = mf * 16 + l15;
      const unsigned addr = (unsigned)((row << 10) + ((n0w + nf * 16 + (lq << 2)) << 1)) ^ (unsigned)((row & 7) << 4);
      *(uint2*)(sA2 + addr) = make_uint2(lo, hi);
    }
  }
  __syncthreads();

  // GEMM3: barrier-free. wave grid 2m x 4n
  const int wm = w & 1, wn = w >> 1;
  const unsigned short* W3b = W3l + ((size_t)(wn * 4) << 9);
  v4f c3[4][4];
#pragma unroll
  for (int mf = 0; mf < 4; mf++)
#pragma unroll
    for (int nf = 0; nf < 4; nf++) c3[mf][nf] = (v4f){0.f, 0.f, 0.f, 0.f};

#pragma unroll 2
  for (int kb3 = 0; kb3 < 512; kb3 += 32){
    v8s a2f[4], w3f[4];
    const unsigned short* W3s = W3b + ((size_t)(kb3 >> 5) << 13);
#pragma unroll
    for (int nf = 0; nf < 4; nf++)
      w3f[nf] = *(const v8s*)(W3s + (nf << 9));
#pragma unroll
    for (int mf = 0; mf < 4; mf++){
      const int row = wm * 64 + mf * 16 + l15;
      a2f[mf] = *(const v8s*)(sA2 + ((unsigned)((row << 10) + ((kb3 + (lq << 3)) << 1)) ^ (unsigned)((row & 7) << 4)));
    }
    __builtin_amdgcn_s_setprio(1);
#pragma unroll
    for (int mf = 0; mf < 4; mf++)
#pragma unroll
      for (int nf = 0; nf < 4; nf++)
        c3[mf][nf] = MFMA16(a2f[mf], w3f[nf], c3[mf][nf]);
    __builtin_amdgcn_s_setprio(0);
  }

  // epilogue: packed NON-TEMPORAL stores into permuted pair slab (2x16B per mf)
  {
    const float b3v0 = b3[wn * 64 +  0 + l15];
    const float b3v1 = b3[wn * 64 + 16 + l15];
    const float b3v2 = b3[wn * 64 + 32 + l15];
    const float b3v3 = b3[wn * 64 + 48 + l15];
    const int seg = q4 * 2 + wm;
    unsigned short* pb = P + ((size_t)p << 17) + ((size_t)l << 3);
#pragma unroll
    for (int mf = 0; mf < 4; mf++){
      v4u h0, h1;
      h0.x = cvt_pk(fmaxf(c3[mf][0][0] + b3v0, 0.f), fmaxf(c3[mf][0][1] + b3v0, 0.f));
      h0.y = cvt_pk(fmaxf(c3[mf][0][2] + b3v0, 0.f), fmaxf(c3[mf][0][3] + b3v0, 0.f));
      h0.z = cvt_pk(fmaxf(c3[mf][1][0] + b3v1, 0.f), fmaxf(c3[mf][1][1] + b3v1, 0.f));
      h0.w = cvt_pk(fmaxf(c3[mf][1][2] + b3v1, 0.f), fmaxf(c3[mf][1][3] + b3v1, 0.f));
      h1.x = cvt_pk(fmaxf(c3[mf][2][0] + b3v2, 0.f), fmaxf(c3[mf][2][1] + b3v2, 0.f));
      h1.y = cvt_pk(fmaxf(c3[mf][2][2] + b3v2, 0.f), fmaxf(c3[mf][2][3] + b3v2, 0.f));
      h1.z = cvt_pk(fmaxf(c3[mf][3][0] + b3v3, 0.f), fmaxf(c3[mf][3][1] + b3v3, 0.f));
      h1.w = cvt_pk(fmaxf(c3[mf][3][2] + b3v3, 0.f), fmaxf(c3[mf][3][3] + b3v3, 0.f));
      const int B = ((seg * 16 + wn * 4 + mf) << 1);
      __builtin_nontemporal_store(h0, (v4u*)(pb + ((size_t)B << 9)));
      __builtin_nontemporal_store(h1, (v4u*)(pb + ((size_t)(B + 1) << 9)));
    }
  }
}

// ---------- slab reduction: out += sum_{15 slabs of i} P (decode permuted) ----------
__global__ __launch_bounds__(256) void k_reduce(const unsigned short* __restrict__ P,
                                                float* __restrict__ out){
  int idx = blockIdx.x * 256 + threadIdx.x;     // 262144 threads, 8 elems each
  const int i = idx >> 14;
  const int g = idx & 16383;                    // = B*64 + l
  const unsigned short* pb = P + (((size_t)(i * 15)) << 17) + ((size_t)g << 3);
  float s[8] = {0.f,0.f,0.f,0.f,0.f,0.f,0.f,0.f};
#pragma unroll
  for (int sl = 0; sl < 15; sl++){
    v8s v = __builtin_nontemporal_load((const v8s*)(pb + ((size_t)sl << 17)));
#pragma unroll
    for (int e = 0; e < 8; e++) s[e] += bf2f((unsigned short)v[e]);
  }
  // decode: B -> (seg, wn, mf, half); l -> (lq, l15); elem j -> (nf&1 = j>>2, e = j&3)
  const int l = g & 63, B = g >> 6;
  const int half = B & 1, mf = (B >> 1) & 3, wn = (B >> 3) & 3, seg = B >> 5;
  const int rowb = (i << 9) + seg * 64 + mf * 16 + ((l >> 4) << 2);
  const int colb = wn * 64 + half * 32 + (l & 15);
  float* ob = out + ((size_t)rowb << 8) + colb;
#pragma unroll
  for (int jj = 0; jj < 2; jj++)
#pragma unroll
    for (int e = 0; e < 4; e++)
      ob[(e << 8) + jj * 16] += s[jj * 4 + e];
}

// ---------- host ----------

extern "C" void kernel_launch(void* const* d_in, const int* in_sizes, int n_in,
                              void* d_out, int out_size, void* d_ws, size_t ws_size,
                              hipStream_t stream){
  const float* objs = (const float*)d_in[0];
  const float* tW1  = (const float*)d_in[1];
  const float* tb1  = (const float*)d_in[2];
  const float* tW2  = (const float*)d_in[3];
  const float* tb2  = (const float*)d_in[4];
  const float* tW3  = (const float*)d_in[5];
  const float* tb3  = (const float*)d_in[6];
  const float* iW1  = (const float*)d_in[7];
  const float* ib1  = (const float*)d_in[8];
  const float* iW2  = (const float*)d_in[9];
  const float* ib2  = (const float*)d_in[10];
  const float* iW3  = (const float*)d_in[11];
  const float* ib3  = (const float*)d_in[12];

  char* ws = (char*)d_ws;
  size_t off = 0;
  unsigned short* objsb = (unsigned short*)(ws + off); off += (size_t)RR * DD * 2;        // 4 MB
  unsigned short* H1    = (unsigned short*)(ws + off); off += (size_t)RR * 512 * 2;       // 8 MB
  unsigned short* H2    = (unsigned short*)(ws + off); off += (size_t)RR * 512 * 2;       // 8 MB
  unsigned short* UVb   = (unsigned short*)(ws + off); off += (size_t)RR * 1024 * 2;      // 16 MB
  unsigned short* Wcat  = (unsigned short*)(ws + off); off += 1536 * 256 * 2;
  unsigned short* tW2t  = (unsigned short*)(ws + off); off += 512 * 512 * 2;
  unsigned short* tW3t  = (unsigned short*)(ws + off); off += 256 * 512 * 2;
  unsigned short* iW2q  = (unsigned short*)(ws + off); off += 512 * 512 * 2;
  unsigned short* iW3q  = (unsigned short*)(ws + off); off += 256 * 512 * 2;
  float*          bcat  = (float*)(ws + off);          off += 1536 * 4;
  unsigned short* P     = (unsigned short*)(ws + off); off += (size_t)240 * 512 * 256 * 2; // 60 MB
  (void)ws_size; (void)in_sizes; (void)n_in; (void)out_size;

  // prep
  k_cast4<<<dim3((RR * DD / 4 + 255) / 256), dim3(256), 0, stream>>>(objs, objsb, RR * DD / 4);
  k_prep<<<dim3(4614), dim3(256), 0, stream>>>(tW1, tW2, tW3, iW1, iW2, iW3, tb1, ib1,
                                               Wcat, tW2t, tW3t, iW2q, iW3q, bcat);

  // merged H1 + UV GEMM (split epilogue): H1 = relu(objs@tW1+tb1), UV = objs@iW1ab + [0|ib1]
  k_gemm<256, true, false, false, true ><<<dim3(RR / 64, 12), dim3(256), 0, stream>>>(
      objsb, Wcat, bcat, H1, nullptr, UVb, RR, 1536);
  // H2 = relu(H1@tW2+tb2)
  k_gemm<512, true, true,  false, false><<<dim3(RR / 64, 4), dim3(256), 0, stream>>>(
      H1, tW2t, tb2, H2, nullptr, nullptr, RR, 512);
  // T path: out = relu(H2@tW3+tb3) + objs
  k_gemm<512, false, true, true,  false><<<dim3(RR / 64, 2), dim3(256), 0, stream>>>(
      H2, tW3t, tb3, d_out, objs, nullptr, RR, DD);

  // fused pair interaction -> bf16 permuted partial slabs (nt stores)
  k_pair2<<<dim3(960), dim3(512), 0, stream>>>(UVb, iW2q, iW3q, ib2, ib3, P);

  // out += sum of 15 slabs per i
  k_reduce<<<dim3(1024), dim3(256), 0, stream>>>(P, (float*)d_out);
}